// Round 1
// baseline (3832.792 us; speedup 1.0000x reference)
//
#include <hip/hip_runtime.h>
#include <stdint.h>
#include <math.h>

// ---------------- problem constants ----------------
#define LSEQ   1024
#define DMODEL 512
#define NH     8
#define DH     64
#define DFF    2048
#define NB     8
#define NLAYER 3
#define UTOP   35      // min(5*ceil(ln(1024)), 1024) = 35
#define NCLS   16

// RNG variant: 0 = partitionable threefry (JAX >= 0.4.36 default): bits = o0^o1 of tf(k2,(0,i))
//              1 = partitionable, low word only: bits = o1
//              2 = legacy (non-partitionable): paired counts scheme
#define RNG_VARIANT 0

// ---------------- threefry2x32 (exact JAX semantics) ----------------
__host__ __device__ __forceinline__ uint32_t rotl32(uint32_t x, int d) {
  return (x << d) | (x >> (32 - d));
}

__host__ __device__ inline void tf2x32(uint32_t k0, uint32_t k1,
                                       uint32_t c0, uint32_t c1,
                                       uint32_t& o0, uint32_t& o1) {
  uint32_t ks2 = k0 ^ k1 ^ 0x1BD11BDAu;
  uint32_t x0 = c0 + k0, x1 = c1 + k1;
#define TF_R4(a,b,c,d) \
  x0 += x1; x1 = rotl32(x1,(a)); x1 ^= x0; \
  x0 += x1; x1 = rotl32(x1,(b)); x1 ^= x0; \
  x0 += x1; x1 = rotl32(x1,(c)); x1 ^= x0; \
  x0 += x1; x1 = rotl32(x1,(d)); x1 ^= x0;
  TF_R4(13,15,26,6)   x0 += k1;  x1 += ks2 + 1u;
  TF_R4(17,29,16,24)  x0 += ks2; x1 += k0 + 2u;
  TF_R4(13,15,26,6)   x0 += k0;  x1 += k1 + 3u;
  TF_R4(17,29,16,24)  x0 += k1;  x1 += ks2 + 4u;
  TF_R4(13,15,26,6)   x0 += ks2; x1 += k0 + 5u;
#undef TF_R4
  o0 = x0; o1 = x1;
}

__global__ void __launch_bounds__(256) gen_idx_kernel(uint32_t k0, uint32_t k1,
                                                      int* idx, int variant) {
  int i = blockIdx.x * 256 + threadIdx.x;
  if (variant <= 1) {
    if (i >= LSEQ * UTOP) return;
    uint32_t a, b;
    tf2x32(k0, k1, 0u, (uint32_t)i, a, b);
    uint32_t bits = (variant == 0) ? (a ^ b) : b;
    idx[i] = (int)(bits & (LSEQ - 1));
  } else {
    const int half = (LSEQ * UTOP) / 2;   // 17920
    if (i >= half) return;
    uint32_t a, b;
    tf2x32(k0, k1, (uint32_t)i, (uint32_t)(i + half), a, b);
    idx[i]        = (int)(a & (LSEQ - 1));
    idx[i + half] = (int)(b & (LSEQ - 1));
  }
}

// ---------------- conv1d (circular pad 1) + positional encoding ----------------
__global__ void __launch_bounds__(512) conv_pe(const float* __restrict__ xe,
                                               const float* __restrict__ w,
                                               float* __restrict__ xout) {
  int bl = blockIdx.x;
  int b = bl >> 10, l = bl & (LSEQ - 1);
  int d = threadIdx.x;
  __shared__ float xs[3][32];
  if (d < 96) {
    int tt = d / 32, c = d % 32;
    int row = (l + tt + LSEQ - 1) & (LSEQ - 1);
    xs[tt][c] = xe[((size_t)b * LSEQ + row) * 32 + c];
  }
  __syncthreads();
  const float* wp = w + (size_t)d * 96;   // conv_w[d][c][t], (D,C,3)
  float acc = 0.f;
  #pragma unroll
  for (int c = 0; c < 32; ++c) {
    acc += xs[0][c] * wp[c * 3 + 0];
    acc += xs[1][c] * wp[c * 3 + 1];
    acc += xs[2][c] * wp[c * 3 + 2];
  }
  // PE: pe[l,2i]=sin(l*div_i), pe[l,2i+1]=cos(l*div_i), div_i=exp(-(2i)*ln(1e4)/512)
  float div = expf((float)(d & ~1) * (-9.210340371976184f / 512.0f));
  float arg = (float)l * div;
  float pe = (d & 1) ? cosf(arg) : sinf(arg);
  xout[((size_t)b * LSEQ + l) * DMODEL + d] = acc + pe;
}

// ---------------- generic tiled SGEMM: C = A(MxK) * W(NxK)^T + bias ----------------
// mode: 0 plain, 1 relu, 2 +resid (row-major MxN), 3 scatter to (B,H,L,dh)
__global__ void __launch_bounds__(256) gemm_nt(const float* __restrict__ A,
                                               const float* __restrict__ W,
                                               const float* __restrict__ bias,
                                               const float* __restrict__ resid,
                                               float* __restrict__ C,
                                               int M, int N, int K, int mode) {
  __shared__ float As[16][64 + 4];
  __shared__ float Ws[16][64 + 4];
  int tid = threadIdx.x;
  int m0 = blockIdx.y * 64, n0 = blockIdx.x * 64;
  int lr = tid >> 2;            // 0..63
  int lc = (tid & 3) << 2;      // 0,4,8,12
  int ty = tid >> 4, tx = tid & 15;
  float acc[4][4] = {};
  for (int k0 = 0; k0 < K; k0 += 16) {
    float4 av = *(const float4*)&A[(size_t)(m0 + lr) * K + k0 + lc];
    float4 wv = *(const float4*)&W[(size_t)(n0 + lr) * K + k0 + lc];
    As[lc + 0][lr] = av.x; As[lc + 1][lr] = av.y; As[lc + 2][lr] = av.z; As[lc + 3][lr] = av.w;
    Ws[lc + 0][lr] = wv.x; Ws[lc + 1][lr] = wv.y; Ws[lc + 2][lr] = wv.z; Ws[lc + 3][lr] = wv.w;
    __syncthreads();
    #pragma unroll
    for (int kk = 0; kk < 16; ++kk) {
      float a0 = As[kk][ty * 4 + 0], a1 = As[kk][ty * 4 + 1];
      float a2 = As[kk][ty * 4 + 2], a3 = As[kk][ty * 4 + 3];
      float b0 = Ws[kk][tx * 4 + 0], b1 = Ws[kk][tx * 4 + 1];
      float b2 = Ws[kk][tx * 4 + 2], b3 = Ws[kk][tx * 4 + 3];
      acc[0][0] += a0 * b0; acc[0][1] += a0 * b1; acc[0][2] += a0 * b2; acc[0][3] += a0 * b3;
      acc[1][0] += a1 * b0; acc[1][1] += a1 * b1; acc[1][2] += a1 * b2; acc[1][3] += a1 * b3;
      acc[2][0] += a2 * b0; acc[2][1] += a2 * b1; acc[2][2] += a2 * b2; acc[2][3] += a2 * b3;
      acc[3][0] += a3 * b0; acc[3][1] += a3 * b1; acc[3][2] += a3 * b2; acc[3][3] += a3 * b3;
    }
    __syncthreads();
  }
  #pragma unroll
  for (int i = 0; i < 4; ++i) {
    int m = m0 + ty * 4 + i;
    #pragma unroll
    for (int j = 0; j < 4; ++j) {
      int n = n0 + tx * 4 + j;
      float v = acc[i][j] + bias[n];
      if (mode == 1) v = fmaxf(v, 0.f);
      if (mode == 2) v += resid[(size_t)m * N + n];
      if (mode == 3) {
        // (b,l) x (h,e)  ->  q[(b*8+h)*1024 + l][e]
        C[(size_t)(m >> 10) * 524288 + (size_t)(n >> 6) * 65536 +
          (size_t)(m & 1023) * 64 + (n & 63)] = v;
      } else {
        C[(size_t)m * N + n] = v;
      }
    }
  }
}

// ---------------- M[b,h,l] = max_u q.k_samp - sum_u(q.k_samp)/L ----------------
__global__ void __launch_bounds__(64) sampled_m(const float* __restrict__ q,
                                                const float* __restrict__ k,
                                                const int* __restrict__ idx,
                                                float* __restrict__ M) {
  int bhl = blockIdx.x;                 // (b*H+h)*L + l
  int l = bhl & (LSEQ - 1);
  int bh = bhl >> 10;
  int t = threadIdx.x;
  __shared__ float qs[DH];
  qs[t] = q[(size_t)bhl * DH + t];
  __syncthreads();
  float vmax = -INFINITY, vsum = 0.f;
  if (t < UTOP) {
    int kr = idx[l * UTOP + t];
    const float4* kp = (const float4*)&k[((size_t)(bh << 10) + kr) * DH];
    const float4* q4 = (const float4*)qs;
    float d = 0.f;
    #pragma unroll
    for (int e = 0; e < DH / 4; ++e) {
      float4 kv = kp[e], qv = q4[e];
      d += qv.x * kv.x + qv.y * kv.y + qv.z * kv.z + qv.w * kv.w;
    }
    vmax = d; vsum = d;
  }
  #pragma unroll
  for (int off = 32; off; off >>= 1) {
    vmax = fmaxf(vmax, __shfl_down(vmax, off));
    vsum += __shfl_down(vsum, off);
  }
  if (t == 0) M[bhl] = vmax - vsum * (1.0f / (float)LSEQ);
}

// ---------------- iterative top-35 per (b,h), tie-break lower index ----------------
__global__ void __launch_bounds__(256) topk35(const float* __restrict__ M,
                                              int* __restrict__ top) {
  int bh = blockIdx.x;
  int t = threadIdx.x;
  __shared__ float mv[LSEQ];
  __shared__ float rv[256];
  __shared__ int   ri[256];
  for (int i = t; i < LSEQ; i += 256) mv[i] = M[(size_t)bh * LSEQ + i];
  __syncthreads();
  for (int it = 0; it < UTOP; ++it) {
    float bestv = -INFINITY; int besti = 0x7fffffff;
    for (int i = t; i < LSEQ; i += 256) {
      float v = mv[i];
      if (v > bestv || (v == bestv && i < besti)) { bestv = v; besti = i; }
    }
    rv[t] = bestv; ri[t] = besti;
    __syncthreads();
    for (int s = 128; s; s >>= 1) {
      if (t < s) {
        float v2 = rv[t + s]; int i2 = ri[t + s];
        if (v2 > rv[t] || (v2 == rv[t] && i2 < ri[t])) { rv[t] = v2; ri[t] = i2; }
      }
      __syncthreads();
    }
    if (t == 0) { top[bh * UTOP + it] = ri[0]; mv[ri[0]] = -INFINITY; }
    __syncthreads();
  }
}

// ---------------- vmean[b,h,e] = mean_l v ----------------
__global__ void __launch_bounds__(64) vmean_k(const float* __restrict__ v,
                                              float* __restrict__ vm) {
  int bh = blockIdx.x, e = threadIdx.x;
  const float* vp = v + (size_t)bh * LSEQ * DH;
  float s = 0.f;
  for (int l = 0; l < LSEQ; ++l) s += vp[(size_t)l * DH + e];
  vm[bh * DH + e] = s * (1.0f / (float)LSEQ);
}

// ---------------- ctx[:,:] = vmean broadcast ----------------
__global__ void __launch_bounds__(256) ctx_fill(const float* __restrict__ vm,
                                                float* __restrict__ ctx) {
  int i = blockIdx.x * 256 + threadIdx.x;   // over B*H*L*DH = 4194304
  int e = i & (DH - 1);
  int bh = i >> 16;                          // L*DH = 65536
  ctx[i] = vm[bh * DH + e];
}

// ---------------- full attention for the 35 selected rows ----------------
__global__ void __launch_bounds__(256) attn_rows(const float* __restrict__ q,
                                                 const float* __restrict__ k,
                                                 const float* __restrict__ v,
                                                 const int* __restrict__ top,
                                                 float* __restrict__ ctx) {
  int bh = blockIdx.x / UTOP;
  int u  = blockIdx.x % UTOP;
  int t = threadIdx.x;
  __shared__ float qs[DH];
  __shared__ float sc[LSEQ];
  __shared__ float red[256];
  __shared__ float part[4][DH];
  int lrow = top[bh * UTOP + u];
  if (t < DH) qs[t] = q[((size_t)bh * LSEQ + lrow) * DH + t];
  __syncthreads();
  float lmax = -INFINITY;
  for (int kk = t; kk < LSEQ; kk += 256) {
    const float4* kp = (const float4*)&k[((size_t)bh * LSEQ + kk) * DH];
    const float4* q4 = (const float4*)qs;
    float d = 0.f;
    #pragma unroll
    for (int e = 0; e < DH / 4; ++e) {
      float4 kv = kp[e], qv = q4[e];
      d += qv.x * kv.x + qv.y * kv.y + qv.z * kv.z + qv.w * kv.w;
    }
    d *= 0.125f;                       // 1/sqrt(64)
    sc[kk] = d;
    lmax = fmaxf(lmax, d);
  }
  red[t] = lmax; __syncthreads();
  for (int s = 128; s; s >>= 1) { if (t < s) red[t] = fmaxf(red[t], red[t + s]); __syncthreads(); }
  float mx = red[0];
  __syncthreads();
  float lsum = 0.f;
  for (int kk = t; kk < LSEQ; kk += 256) { float p = expf(sc[kk] - mx); sc[kk] = p; lsum += p; }
  red[t] = lsum; __syncthreads();
  for (int s = 128; s; s >>= 1) { if (t < s) red[t] += red[t + s]; __syncthreads(); }
  float inv = 1.0f / red[0];
  __syncthreads();
  int e = t & (DH - 1), c = t >> 6;
  float acc = 0.f;
  for (int kk = c * 256; kk < (c + 1) * 256; ++kk)
    acc += sc[kk] * v[((size_t)bh * LSEQ + kk) * DH + e];
  part[c][e] = acc; __syncthreads();
  if (t < DH) {
    float s4 = (part[0][t] + part[1][t] + part[2][t] + part[3][t]) * inv;
    ctx[((size_t)bh * LSEQ + lrow) * DH + t] = s4;
  }
}

// ---------------- layernorm over D=512 (input already has residual added) ----------------
__global__ void __launch_bounds__(256) ln_k(const float* __restrict__ in,
                                            const float* __restrict__ g,
                                            const float* __restrict__ be,
                                            float* __restrict__ out) {
  int row = blockIdx.x, t = threadIdx.x;
  const float* p = in + (size_t)row * DMODEL;
  float x0 = p[t], x1 = p[t + 256];
  __shared__ float red[256];
  red[t] = x0 + x1; __syncthreads();
  for (int s = 128; s; s >>= 1) { if (t < s) red[t] += red[t + s]; __syncthreads(); }
  float mean = red[0] * (1.0f / DMODEL);
  __syncthreads();
  float d0 = x0 - mean, d1 = x1 - mean;
  red[t] = d0 * d0 + d1 * d1; __syncthreads();
  for (int s = 128; s; s >>= 1) { if (t < s) red[t] += red[t + s]; __syncthreads(); }
  float rstd = 1.0f / sqrtf(red[0] * (1.0f / DMODEL) + 1e-5f);
  out[(size_t)row * DMODEL + t]       = d0 * rstd * g[t] + be[t];
  out[(size_t)row * DMODEL + t + 256] = d1 * rstd * g[t + 256] + be[t + 256];
}

// ---------------- final: out[b,c] = sum_i x[b,i]*mark[b,i>>9]*fc_w[c,i] + fc_b[c] ----------------
__global__ void __launch_bounds__(256) final_fc(const float* __restrict__ x,
                                                const float* __restrict__ mark,
                                                const float* __restrict__ fw,
                                                const float* __restrict__ fb,
                                                float* __restrict__ out) {
  int b = blockIdx.x >> 4, c = blockIdx.x & 15;
  int t = threadIdx.x;
  const float* xp = x + (size_t)b * (LSEQ * DMODEL);
  const float* wp = fw + (size_t)c * (LSEQ * DMODEL);
  const float* mp = mark + (size_t)b * LSEQ;
  float acc = 0.f;
  for (int i = t; i < LSEQ * DMODEL; i += 256)
    acc += xp[i] * mp[i >> 9] * wp[i];
  __shared__ float red[256];
  red[t] = acc; __syncthreads();
  for (int s = 128; s; s >>= 1) { if (t < s) red[t] += red[t + s]; __syncthreads(); }
  if (t == 0) out[b * NCLS + c] = red[0] + fb[c];
}

// ---------------- host launch ----------------
extern "C" void kernel_launch(void* const* d_in, const int* in_sizes, int n_in,
                              void* d_out, int out_size, void* d_ws, size_t ws_size,
                              hipStream_t stream) {
  (void)in_sizes; (void)n_in; (void)out_size; (void)ws_size;
  const float* x_enc  = (const float*)d_in[0];
  const float* x_mark = (const float*)d_in[1];
  const float* conv_w = (const float*)d_in[2];
  const float* Wq = (const float*)d_in[3];
  const float* bq = (const float*)d_in[4];
  const float* Wk = (const float*)d_in[5];
  const float* bk = (const float*)d_in[6];
  const float* Wv = (const float*)d_in[7];
  const float* bv = (const float*)d_in[8];
  const float* Wo = (const float*)d_in[9];
  const float* bo = (const float*)d_in[10];
  const float* W1 = (const float*)d_in[11];
  const float* b1 = (const float*)d_in[12];
  const float* W2 = (const float*)d_in[13];
  const float* b2 = (const float*)d_in[14];
  const float* g1 = (const float*)d_in[15];
  const float* be1= (const float*)d_in[16];
  const float* g2 = (const float*)d_in[17];
  const float* be2= (const float*)d_in[18];
  const float* gF = (const float*)d_in[19];
  const float* bF = (const float*)d_in[20];
  const float* fcw= (const float*)d_in[21];
  const float* fcb= (const float*)d_in[22];
  float* out = (float*)d_out;

  const size_t NBLD = (size_t)NB * LSEQ * DMODEL;       // 4,194,304 floats
  float* ws  = (float*)d_ws;
  float* xb  = ws;                       // current activations (B,L,D)
  float* tmp = xb  + NBLD;               // ctx buffer / pre-LN sum
  float* qb  = tmp + NBLD;               // (B,H,L,dh)
  float* kb  = qb  + NBLD;
  float* vb  = kb  + NBLD;
  float* hid = vb  + NBLD;               // (B,L,Dff) = 16,777,216 floats
  float* Mb  = hid + (size_t)NB * LSEQ * DFF;
  float* vm  = Mb  + (size_t)NB * NH * LSEQ;
  int* idxb  = (int*)(vm + NB * NH * DH);
  int* topb  = idxb + LSEQ * UTOP;
  // total ~144.5 MB of d_ws

  conv_pe<<<NB * LSEQ, DMODEL, 0, stream>>>(x_enc, conv_w, xb);

  dim3 g512(DMODEL / 64, (NB * LSEQ) / 64);   // (8, 128)
  dim3 gff (DFF / 64,    (NB * LSEQ) / 64);   // (32, 128)

  for (int l = 0; l < NLAYER; ++l) {
    const float* Wql = Wq + (size_t)l * DMODEL * DMODEL;
    const float* Wkl = Wk + (size_t)l * DMODEL * DMODEL;
    const float* Wvl = Wv + (size_t)l * DMODEL * DMODEL;
    const float* Wol = Wo + (size_t)l * DMODEL * DMODEL;
    const float* W1l = W1 + (size_t)l * DFF * DMODEL;
    const float* W2l = W2 + (size_t)l * DMODEL * DFF;

    gemm_nt<<<g512, 256, 0, stream>>>(xb, Wql, bq + l * DMODEL, nullptr, qb,
                                      NB * LSEQ, DMODEL, DMODEL, 3);
    gemm_nt<<<g512, 256, 0, stream>>>(xb, Wkl, bk + l * DMODEL, nullptr, kb,
                                      NB * LSEQ, DMODEL, DMODEL, 3);
    gemm_nt<<<g512, 256, 0, stream>>>(xb, Wvl, bv + l * DMODEL, nullptr, vb,
                                      NB * LSEQ, DMODEL, DMODEL, 3);

    // JAX threefry key derivation (host-side, deterministic):
    // lk = fold_in(key(42), l) ; k2 = second subkey of split(lk)
    uint32_t lk0, lk1, k2_0, k2_1;
    tf2x32(0u, 42u, 0u, (uint32_t)l, lk0, lk1);
#if RNG_VARIANT <= 1
    tf2x32(lk0, lk1, 0u, 1u, k2_0, k2_1);                 // foldlike split: tf(lk,(0,1))
#else
    { uint32_t a0, a1, b0, b1;
      tf2x32(lk0, lk1, 0u, 2u, a0, a1);
      tf2x32(lk0, lk1, 1u, 3u, b0, b1);
      k2_0 = a1; k2_1 = b1; }                             // legacy split row 1
#endif
    gen_idx_kernel<<<140, 256, 0, stream>>>(k2_0, k2_1, idxb, RNG_VARIANT);

    sampled_m<<<NB * NH * LSEQ, 64, 0, stream>>>(qb, kb, idxb, Mb);
    topk35<<<NB * NH, 256, 0, stream>>>(Mb, topb);
    vmean_k<<<NB * NH, 64, 0, stream>>>(vb, vm);
    ctx_fill<<<(NB * NH * LSEQ * DH) / 256, 256, 0, stream>>>(vm, tmp);
    attn_rows<<<NB * NH * UTOP, 256, 0, stream>>>(qb, kb, vb, topb, tmp);

    // x + ctx@Wo^T + bo  -> hid(first 16MB);  LN -> xb
    gemm_nt<<<g512, 256, 0, stream>>>(tmp, Wol, bo + l * DMODEL, xb, hid,
                                      NB * LSEQ, DMODEL, DMODEL, 2);
    ln_k<<<NB * LSEQ, 256, 0, stream>>>(hid, g1 + l * DMODEL, be1 + l * DMODEL, xb);

    // FFN
    gemm_nt<<<gff, 256, 0, stream>>>(xb, W1l, b1 + l * DFF, nullptr, hid,
                                     NB * LSEQ, DFF, DMODEL, 1);
    gemm_nt<<<g512, 256, 0, stream>>>(hid, W2l, b2 + l * DMODEL, xb, tmp,
                                      NB * LSEQ, DMODEL, DFF, 2);
    ln_k<<<NB * LSEQ, 256, 0, stream>>>(tmp, g2 + l * DMODEL, be2 + l * DMODEL, xb);
  }

  ln_k<<<NB * LSEQ, 256, 0, stream>>>(xb, gF, bF, tmp);
  final_fc<<<NB * NCLS, 256, 0, stream>>>(tmp, x_mark, fcw, fcb, out);
}

// Round 2
// 2312.446 us; speedup vs baseline: 1.6575x; 1.6575x over previous
//
#include <hip/hip_runtime.h>
#include <stdint.h>
#include <math.h>

// ---------------- problem constants ----------------
#define LSEQ   1024
#define DMODEL 512
#define NH     8
#define DH     64
#define DFF    2048
#define NB     8
#define NLAYER 3
#define UTOP   35
#define NCLS   16

typedef unsigned short u16;
typedef __attribute__((ext_vector_type(8))) short short8;
typedef __attribute__((ext_vector_type(4))) float f32x4;

// bf16 helpers (RNE)
__device__ __forceinline__ u16 f2bf(float f) {
  unsigned int u = __float_as_uint(f);
  unsigned int r = (u + 0x7fffu + ((u >> 16) & 1u)) >> 16;
  return (u16)r;
}
__device__ __forceinline__ float bf2f(u16 h) {
  return __uint_as_float(((unsigned int)h) << 16);
}

#define GLDS16(gsrc, ldst)                                                        \
  __builtin_amdgcn_global_load_lds(                                              \
      (const __attribute__((address_space(1))) void*)(gsrc),                     \
      (__attribute__((address_space(3))) void*)(ldst), 16, 0, 0)

// ---------------- threefry2x32 (exact JAX semantics) ----------------
__host__ __device__ __forceinline__ uint32_t rotl32(uint32_t x, int d) {
  return (x << d) | (x >> (32 - d));
}
__host__ __device__ inline void tf2x32(uint32_t k0, uint32_t k1,
                                       uint32_t c0, uint32_t c1,
                                       uint32_t& o0, uint32_t& o1) {
  uint32_t ks2 = k0 ^ k1 ^ 0x1BD11BDAu;
  uint32_t x0 = c0 + k0, x1 = c1 + k1;
#define TF_R4(a,b,c,d) \
  x0 += x1; x1 = rotl32(x1,(a)); x1 ^= x0; \
  x0 += x1; x1 = rotl32(x1,(b)); x1 ^= x0; \
  x0 += x1; x1 = rotl32(x1,(c)); x1 ^= x0; \
  x0 += x1; x1 = rotl32(x1,(d)); x1 ^= x0;
  TF_R4(13,15,26,6)   x0 += k1;  x1 += ks2 + 1u;
  TF_R4(17,29,16,24)  x0 += ks2; x1 += k0 + 2u;
  TF_R4(13,15,26,6)   x0 += k0;  x1 += k1 + 3u;
  TF_R4(17,29,16,24)  x0 += k1;  x1 += ks2 + 4u;
  TF_R4(13,15,26,6)   x0 += ks2; x1 += k0 + 5u;
#undef TF_R4
  o0 = x0; o1 = x1;
}

__global__ void __launch_bounds__(256) gen_idx_kernel(uint32_t k0, uint32_t k1,
                                                      int* idx) {
  int i = blockIdx.x * 256 + threadIdx.x;
  if (i >= LSEQ * UTOP) return;
  uint32_t a, b;
  tf2x32(k0, k1, 0u, (uint32_t)i, a, b);
  idx[i] = (int)((a ^ b) & (LSEQ - 1));
}

// ---------------- fp32 -> bf16 hi/lo split ----------------
__global__ void __launch_bounds__(256) cvt_split(const float* __restrict__ src,
                                                 u16* __restrict__ dh,
                                                 u16* __restrict__ dl, int n4) {
  int i = blockIdx.x * 256 + threadIdx.x;
  if (i >= n4) return;
  float4 v = *(const float4*)&src[i * 4];
  ushort4 h, l;
  h.x = f2bf(v.x); l.x = f2bf(v.x - bf2f(h.x));
  h.y = f2bf(v.y); l.y = f2bf(v.y - bf2f(h.y));
  h.z = f2bf(v.z); l.z = f2bf(v.z - bf2f(h.z));
  h.w = f2bf(v.w); l.w = f2bf(v.w - bf2f(h.w));
  *(ushort4*)&dh[i * 4] = h;
  *(ushort4*)&dl[i * 4] = l;
}

// ---------------- conv1d (circular pad 1) + positional encoding ----------------
__global__ void __launch_bounds__(512) conv_pe(const float* __restrict__ xe,
                                               const float* __restrict__ w,
                                               float* __restrict__ xout,
                                               u16* __restrict__ xh,
                                               u16* __restrict__ xl) {
  int bl = blockIdx.x;
  int b = bl >> 10, l = bl & (LSEQ - 1);
  int d = threadIdx.x;
  __shared__ float xs[3][32];
  if (d < 96) {
    int tt = d / 32, c = d % 32;
    int row = (l + tt + LSEQ - 1) & (LSEQ - 1);
    xs[tt][c] = xe[((size_t)b * LSEQ + row) * 32 + c];
  }
  __syncthreads();
  const float* wp = w + (size_t)d * 96;
  float acc = 0.f;
  #pragma unroll
  for (int c = 0; c < 32; ++c) {
    acc += xs[0][c] * wp[c * 3 + 0];
    acc += xs[1][c] * wp[c * 3 + 1];
    acc += xs[2][c] * wp[c * 3 + 2];
  }
  float div = expf((float)(d & ~1) * (-9.210340371976184f / 512.0f));
  float arg = (float)l * div;
  float pe = (d & 1) ? cosf(arg) : sinf(arg);
  float v = acc + pe;
  size_t o = ((size_t)b * LSEQ + l) * DMODEL + d;
  xout[o] = v;
  u16 h = f2bf(v);
  xh[o] = h;
  xl[o] = f2bf(v - bf2f(h));
}

// ---------------- split-bf16 MFMA GEMM: C = A(MxK)*W(NxK)^T + bias ----------------
// 3 passes: Ah*Wh + Ah*Wl + Al*Wh  (error ~4e-6 relative)
// mode: 1 = relu -> bf16 hi/lo out; 2 = +resid -> fp32 out; 3 = scatter (B,H,L,dh) fp32
__global__ void __launch_bounds__(256) gemm_bf16(
    const u16* __restrict__ Ah, const u16* __restrict__ Al,
    const u16* __restrict__ Wh, const u16* __restrict__ Wl,
    const float* __restrict__ bias, const float* __restrict__ resid,
    float* __restrict__ Cf, u16* __restrict__ Chi, u16* __restrict__ Clo,
    int M, int N, int K, int mode) {
  __shared__ u16 As[128 * 64];
  __shared__ u16 Bs[128 * 64];
  const int tid = threadIdx.x;
  const int lane = tid & 63, wv = tid >> 6;
  const int wm = wv >> 1, wn = wv & 1;
  const int m0 = blockIdx.y * 128, n0 = blockIdx.x * 128;
  const int lrow = lane >> 3;               // row within 8-row segment
  const int kgS = (lane & 7) ^ lrow;        // inverse-swizzled source k-group

  f32x4 acc[4][4];
  #pragma unroll
  for (int i = 0; i < 4; ++i)
    #pragma unroll
    for (int j = 0; j < 4; ++j) acc[i][j] = (f32x4){0.f, 0.f, 0.f, 0.f};

  for (int pass = 0; pass < 3; ++pass) {
    const u16* Ap = (pass == 2) ? Al : Ah;
    const u16* Wp = (pass == 1) ? Wl : Wh;
    for (int k0 = 0; k0 < K; k0 += 64) {
      #pragma unroll
      for (int r = 0; r < 4; ++r) {
        int seg = wv * 4 + r;                         // 0..15 (8 rows each)
        int row = seg * 8 + lrow;
        const u16* ga = Ap + (size_t)(m0 + row) * K + k0 + kgS * 8;
        GLDS16(ga, &As[seg * 512]);
        const u16* gb = Wp + (size_t)(n0 + row) * K + k0 + kgS * 8;
        GLDS16(gb, &Bs[seg * 512]);
      }
      __syncthreads();
      #pragma unroll
      for (int kk = 0; kk < 2; ++kk) {
        int kg = kk * 4 + (lane >> 4);
        short8 af[4], bfr[4];
        #pragma unroll
        for (int mi = 0; mi < 4; ++mi) {
          int row = wm * 64 + mi * 16 + (lane & 15);
          af[mi] = *(const short8*)&As[row * 64 + ((kg ^ (row & 7)) << 3)];
        }
        #pragma unroll
        for (int ni = 0; ni < 4; ++ni) {
          int row = wn * 64 + ni * 16 + (lane & 15);
          bfr[ni] = *(const short8*)&Bs[row * 64 + ((kg ^ (row & 7)) << 3)];
        }
        #pragma unroll
        for (int mi = 0; mi < 4; ++mi)
          #pragma unroll
          for (int ni = 0; ni < 4; ++ni)
            acc[mi][ni] = __builtin_amdgcn_mfma_f32_16x16x32_bf16(
                af[mi], bfr[ni], acc[mi][ni], 0, 0, 0);
      }
      __syncthreads();
    }
  }

  // epilogue: C/D layout col = lane&15, row = (lane>>4)*4 + reg  [m89 verified]
  const int colb = n0 + wn * 64 + (lane & 15);
  const int rowb = m0 + wm * 64 + ((lane >> 4) << 2);
  #pragma unroll
  for (int mi = 0; mi < 4; ++mi) {
    #pragma unroll
    for (int ni = 0; ni < 4; ++ni) {
      int gcol = colb + ni * 16;
      float bv = bias[gcol];
      #pragma unroll
      for (int j = 0; j < 4; ++j) {
        int grow = rowb + mi * 16 + j;
        float v = acc[mi][ni][j] + bv;
        if (mode == 1) {
          size_t o = (size_t)grow * N + gcol;
          float vr = fmaxf(v, 0.f);
          u16 h = f2bf(vr);
          Chi[o] = h;
          Clo[o] = f2bf(vr - bf2f(h));
        } else if (mode == 2) {
          size_t o = (size_t)grow * N + gcol;
          Cf[o] = v + resid[o];
        } else {  // 3: scatter to (B,H,L,dh)
          Cf[(size_t)(grow >> 10) * (NH * LSEQ * DH) +
             (size_t)(gcol >> 6) * (LSEQ * DH) +
             (size_t)(grow & (LSEQ - 1)) * DH + (gcol & (DH - 1))] = v;
        }
      }
    }
  }
}

// ---------------- M[b,h,l] = max_u q.k_samp - sum_u(q.k_samp)/L ----------------
__global__ void __launch_bounds__(64) sampled_m(const float* __restrict__ q,
                                                const float* __restrict__ k,
                                                const int* __restrict__ idx,
                                                float* __restrict__ M) {
  int bhl = blockIdx.x;
  int l = bhl & (LSEQ - 1);
  int bh = bhl >> 10;
  int t = threadIdx.x;
  __shared__ float qs[DH];
  qs[t] = q[(size_t)bhl * DH + t];
  __syncthreads();
  float vmax = -INFINITY, vsum = 0.f;
  if (t < UTOP) {
    int kr = idx[l * UTOP + t];
    const float4* kp = (const float4*)&k[((size_t)(bh << 10) + kr) * DH];
    const float4* q4 = (const float4*)qs;
    float d = 0.f;
    #pragma unroll
    for (int e = 0; e < DH / 4; ++e) {
      float4 kv = kp[e], qv = q4[e];
      d += qv.x * kv.x + qv.y * kv.y + qv.z * kv.z + qv.w * kv.w;
    }
    vmax = d; vsum = d;
  }
  #pragma unroll
  for (int off = 32; off; off >>= 1) {
    vmax = fmaxf(vmax, __shfl_down(vmax, off));
    vsum += __shfl_down(vsum, off);
  }
  if (t == 0) M[bhl] = vmax - vsum * (1.0f / (float)LSEQ);
}

// ---------------- iterative top-35 per (b,h) ----------------
__global__ void __launch_bounds__(256) topk35(const float* __restrict__ M,
                                              int* __restrict__ top) {
  int bh = blockIdx.x;
  int t = threadIdx.x;
  __shared__ float mv[LSEQ];
  __shared__ float rv[256];
  __shared__ int   ri[256];
  for (int i = t; i < LSEQ; i += 256) mv[i] = M[(size_t)bh * LSEQ + i];
  __syncthreads();
  for (int it = 0; it < UTOP; ++it) {
    float bestv = -INFINITY; int besti = 0x7fffffff;
    for (int i = t; i < LSEQ; i += 256) {
      float v = mv[i];
      if (v > bestv || (v == bestv && i < besti)) { bestv = v; besti = i; }
    }
    rv[t] = bestv; ri[t] = besti;
    __syncthreads();
    for (int s = 128; s; s >>= 1) {
      if (t < s) {
        float v2 = rv[t + s]; int i2 = ri[t + s];
        if (v2 > rv[t] || (v2 == rv[t] && i2 < ri[t])) { rv[t] = v2; ri[t] = i2; }
      }
      __syncthreads();
    }
    if (t == 0) { top[bh * UTOP + it] = ri[0]; mv[ri[0]] = -INFINITY; }
    __syncthreads();
  }
}

// ---------------- vmean[b,h,e] = mean_l v ----------------
__global__ void __launch_bounds__(64) vmean_k(const float* __restrict__ v,
                                              float* __restrict__ vm) {
  int bh = blockIdx.x, e = threadIdx.x;
  const float* vp = v + (size_t)bh * LSEQ * DH;
  float s = 0.f;
  for (int l = 0; l < LSEQ; ++l) s += vp[(size_t)l * DH + e];
  vm[bh * DH + e] = s * (1.0f / (float)LSEQ);
}

__global__ void __launch_bounds__(256) ctx_fill(const float* __restrict__ vm,
                                                float* __restrict__ ctx) {
  int i = blockIdx.x * 256 + threadIdx.x;
  int e = i & (DH - 1);
  int bh = i >> 16;
  ctx[i] = vm[bh * DH + e];
}

// ---------------- full attention for the 35 selected rows ----------------
__global__ void __launch_bounds__(256) attn_rows(const float* __restrict__ q,
                                                 const float* __restrict__ k,
                                                 const float* __restrict__ v,
                                                 const int* __restrict__ top,
                                                 float* __restrict__ ctx) {
  int bh = blockIdx.x / UTOP;
  int u  = blockIdx.x % UTOP;
  int t = threadIdx.x;
  __shared__ float qs[DH];
  __shared__ float sc[LSEQ];
  __shared__ float red[256];
  __shared__ float part[4][DH];
  int lrow = top[bh * UTOP + u];
  if (t < DH) qs[t] = q[((size_t)bh * LSEQ + lrow) * DH + t];
  __syncthreads();
  float lmax = -INFINITY;
  for (int kk = t; kk < LSEQ; kk += 256) {
    const float4* kp = (const float4*)&k[((size_t)bh * LSEQ + kk) * DH];
    const float4* q4 = (const float4*)qs;
    float d = 0.f;
    #pragma unroll
    for (int e = 0; e < DH / 4; ++e) {
      float4 kv = kp[e], qv = q4[e];
      d += qv.x * kv.x + qv.y * kv.y + qv.z * kv.z + qv.w * kv.w;
    }
    d *= 0.125f;
    sc[kk] = d;
    lmax = fmaxf(lmax, d);
  }
  red[t] = lmax; __syncthreads();
  for (int s = 128; s; s >>= 1) { if (t < s) red[t] = fmaxf(red[t], red[t + s]); __syncthreads(); }
  float mx = red[0];
  __syncthreads();
  float lsum = 0.f;
  for (int kk = t; kk < LSEQ; kk += 256) { float p = expf(sc[kk] - mx); sc[kk] = p; lsum += p; }
  red[t] = lsum; __syncthreads();
  for (int s = 128; s; s >>= 1) { if (t < s) red[t] += red[t + s]; __syncthreads(); }
  float inv = 1.0f / red[0];
  __syncthreads();
  int e = t & (DH - 1), c = t >> 6;
  float acc = 0.f;
  for (int kk = c * 256; kk < (c + 1) * 256; ++kk)
    acc += sc[kk] * v[((size_t)bh * LSEQ + kk) * DH + e];
  part[c][e] = acc; __syncthreads();
  if (t < DH) {
    float s4 = (part[0][t] + part[1][t] + part[2][t] + part[3][t]) * inv;
    ctx[((size_t)bh * LSEQ + lrow) * DH + t] = s4;
  }
}

// ---------------- layernorm over D=512; optional bf16 hi/lo out, optional mark ----
__global__ void __launch_bounds__(256) ln_k(const float* __restrict__ in,
                                            const float* __restrict__ g,
                                            const float* __restrict__ be,
                                            float* __restrict__ out,
                                            u16* __restrict__ oh,
                                            u16* __restrict__ ol,
                                            const float* __restrict__ mark) {
  int row = blockIdx.x, t = threadIdx.x;
  const float* p = in + (size_t)row * DMODEL;
  float x0 = p[t], x1 = p[t + 256];
  __shared__ float red[256];
  red[t] = x0 + x1; __syncthreads();
  for (int s = 128; s; s >>= 1) { if (t < s) red[t] += red[t + s]; __syncthreads(); }
  float mean = red[0] * (1.0f / DMODEL);
  __syncthreads();
  float d0 = x0 - mean, d1 = x1 - mean;
  red[t] = d0 * d0 + d1 * d1; __syncthreads();
  for (int s = 128; s; s >>= 1) { if (t < s) red[t] += red[t + s]; __syncthreads(); }
  float rstd = 1.0f / sqrtf(red[0] * (1.0f / DMODEL) + 1e-5f);
  float v0 = d0 * rstd * g[t] + be[t];
  float v1 = d1 * rstd * g[t + 256] + be[t + 256];
  if (mark) { float mk = mark[row]; v0 *= mk; v1 *= mk; }
  size_t o0 = (size_t)row * DMODEL + t, o1 = o0 + 256;
  out[o0] = v0; out[o1] = v1;
  if (oh) {
    u16 h0 = f2bf(v0), h1 = f2bf(v1);
    oh[o0] = h0; ol[o0] = f2bf(v0 - bf2f(h0));
    oh[o1] = h1; ol[o1] = f2bf(v1 - bf2f(h1));
  }
}

// ---------------- final fc: split-K two-stage ----------------
__global__ void __launch_bounds__(256) fc_stage1(const float* __restrict__ y,
                                                 const float* __restrict__ fw,
                                                 float* __restrict__ part) {
  int blk = blockIdx.x;                 // 512 blocks, 1024 k each
  int k0 = blk * 1024;
  int tid = threadIdx.x;
  __shared__ float ys[NB][1024];
  #pragma unroll
  for (int b = 0; b < NB; ++b)
    *(float4*)&ys[b][tid * 4] = *(const float4*)&y[(size_t)b * (LSEQ * DMODEL) + k0 + tid * 4];
  __syncthreads();
  int c = tid & 15, ks = tid >> 4;      // 16 classes x 16 k-slices(64 each)
  float acc[NB] = {};
  const float* wp = fw + (size_t)c * (LSEQ * DMODEL) + k0 + ks * 64;
  for (int j = 0; j < 16; ++j) {
    int jj = (j + ks) & 15;             // stagger to avoid LDS bank clash
    float4 w4 = *(const float4*)&wp[jj * 4];
    #pragma unroll
    for (int b = 0; b < NB; ++b) {
      float4 yv = *(const float4*)&ys[b][ks * 64 + jj * 4];
      acc[b] += yv.x * w4.x + yv.y * w4.y + yv.z * w4.z + yv.w * w4.w;
    }
  }
  __shared__ float rs[16][128];
  #pragma unroll
  for (int b = 0; b < NB; ++b) rs[ks][b * 16 + c] = acc[b];
  __syncthreads();
  if (tid < 128) {
    float s = 0.f;
    #pragma unroll
    for (int i = 0; i < 16; ++i) s += rs[i][tid];
    part[(size_t)tid * 512 + blk] = s;   // part[bc][blk]
  }
}

__global__ void __launch_bounds__(128) fc_stage2(const float* __restrict__ part,
                                                 const float* __restrict__ fb,
                                                 float* __restrict__ out) {
  int bc = threadIdx.x;                 // b*16+c
  float s = 0.f;
  for (int i = 0; i < 512; ++i) s += part[(size_t)bc * 512 + i];
  out[bc] = s + fb[bc & 15];
}

// ---------------- host launch ----------------
extern "C" void kernel_launch(void* const* d_in, const int* in_sizes, int n_in,
                              void* d_out, int out_size, void* d_ws, size_t ws_size,
                              hipStream_t stream) {
  (void)in_sizes; (void)n_in; (void)out_size; (void)ws_size;
  const float* x_enc  = (const float*)d_in[0];
  const float* x_mark = (const float*)d_in[1];
  const float* conv_w = (const float*)d_in[2];
  const float* Wq = (const float*)d_in[3];
  const float* bq = (const float*)d_in[4];
  const float* Wk = (const float*)d_in[5];
  const float* bk = (const float*)d_in[6];
  const float* Wv = (const float*)d_in[7];
  const float* bv = (const float*)d_in[8];
  const float* Wo = (const float*)d_in[9];
  const float* bo = (const float*)d_in[10];
  const float* W1 = (const float*)d_in[11];
  const float* b1 = (const float*)d_in[12];
  const float* W2 = (const float*)d_in[13];
  const float* b2 = (const float*)d_in[14];
  const float* g1 = (const float*)d_in[15];
  const float* be1= (const float*)d_in[16];
  const float* g2 = (const float*)d_in[17];
  const float* be2= (const float*)d_in[18];
  const float* gF = (const float*)d_in[19];
  const float* bF = (const float*)d_in[20];
  const float* fcw= (const float*)d_in[21];
  const float* fcb= (const float*)d_in[22];
  float* out = (float*)d_out;

  const size_t NBLD = (size_t)NB * LSEQ * DMODEL;       // 4,194,304
  float* ws  = (float*)d_ws;
  float* xb  = ws;
  float* tmp = xb  + NBLD;
  float* qb  = tmp + NBLD;
  float* kb  = qb  + NBLD;
  float* vb  = kb  + NBLD;
  u16*  xh   = (u16*)(vb + NBLD);
  u16*  xl   = xh + NBLD;
  u16*  ch   = xl + NBLD;      // ctx hi
  u16*  cl   = ch + NBLD;      // ctx lo
  u16*  Whb  = cl + NBLD;      // per-layer weights hi (3,145,728 u16)
  u16*  Wlb  = Whb + 3145728;
  float* Mb  = (float*)(Wlb + 3145728);
  float* vm  = Mb + (size_t)NB * NH * LSEQ;
  float* part= vm + NB * NH * DH;
  int* idxb  = (int*)(part + 512 * 128);
  int* topb  = idxb + LSEQ * UTOP;
  // FFN hidden bf16 hi/lo aliased into dead fp32 regions:
  u16* hidh  = (u16*)kb;       // spans kb..vb  (16,777,216 u16)  exact fit
  u16* hidl  = (u16*)tmp;      // spans tmp..qb (16,777,216 u16)  exact fit
  // total ws ~131 MB

  conv_pe<<<NB * LSEQ, DMODEL, 0, stream>>>(x_enc, conv_w, xb, xh, xl);

  dim3 g512(4, 64);    // N=512 GEMMs
  dim3 gff (16, 64);   // N=2048 GEMM

  for (int l = 0; l < NLAYER; ++l) {
    // per-layer weight split (hi/lo)
    cvt_split<<<262144/1024 + 1, 256, 0, stream>>>(Wq + (size_t)l*262144, Whb + 0,       Wlb + 0,       262144/4);
    cvt_split<<<262144/1024 + 1, 256, 0, stream>>>(Wk + (size_t)l*262144, Whb + 262144,  Wlb + 262144,  262144/4);
    cvt_split<<<262144/1024 + 1, 256, 0, stream>>>(Wv + (size_t)l*262144, Whb + 524288,  Wlb + 524288,  262144/4);
    cvt_split<<<262144/1024 + 1, 256, 0, stream>>>(Wo + (size_t)l*262144, Whb + 786432,  Wlb + 786432,  262144/4);
    cvt_split<<<1048576/1024 + 1, 256, 0, stream>>>(W1 + (size_t)l*1048576, Whb + 1048576, Wlb + 1048576, 1048576/4);
    cvt_split<<<1048576/1024 + 1, 256, 0, stream>>>(W2 + (size_t)l*1048576, Whb + 2097152, Wlb + 2097152, 1048576/4);

    // QKV (mode 3: scatter to (B,H,L,dh))
    gemm_bf16<<<g512, 256, 0, stream>>>(xh, xl, Whb + 0,      Wlb + 0,      bq + l*DMODEL, nullptr, qb, nullptr, nullptr, NB*LSEQ, DMODEL, DMODEL, 3);
    gemm_bf16<<<g512, 256, 0, stream>>>(xh, xl, Whb + 262144, Wlb + 262144, bk + l*DMODEL, nullptr, kb, nullptr, nullptr, NB*LSEQ, DMODEL, DMODEL, 3);
    gemm_bf16<<<g512, 256, 0, stream>>>(xh, xl, Whb + 524288, Wlb + 524288, bv + l*DMODEL, nullptr, vb, nullptr, nullptr, NB*LSEQ, DMODEL, DMODEL, 3);

    // prob-attention
    uint32_t lk0, lk1, k2_0, k2_1;
    tf2x32(0u, 42u, 0u, (uint32_t)l, lk0, lk1);
    tf2x32(lk0, lk1, 0u, 1u, k2_0, k2_1);
    gen_idx_kernel<<<140, 256, 0, stream>>>(k2_0, k2_1, idxb);
    sampled_m<<<NB * NH * LSEQ, 64, 0, stream>>>(qb, kb, idxb, Mb);
    topk35<<<NB * NH, 256, 0, stream>>>(Mb, topb);
    vmean_k<<<NB * NH, 64, 0, stream>>>(vb, vm);
    ctx_fill<<<(NB * NH * LSEQ * DH) / 256, 256, 0, stream>>>(vm, tmp);
    attn_rows<<<NB * NH * UTOP, 256, 0, stream>>>(qb, kb, vb, topb, tmp);

    // ctx -> bf16 hi/lo
    cvt_split<<<NBLD / 1024, 256, 0, stream>>>(tmp, ch, cl, NBLD / 4);

    // Wo GEMM (+resid xb) -> qb ; LN1 -> xb (+hi/lo)
    gemm_bf16<<<g512, 256, 0, stream>>>(ch, cl, Whb + 786432, Wlb + 786432, bo + l*DMODEL, xb, qb, nullptr, nullptr, NB*LSEQ, DMODEL, DMODEL, 2);
    ln_k<<<NB * LSEQ, 256, 0, stream>>>(qb, g1 + l*DMODEL, be1 + l*DMODEL, xb, xh, xl, nullptr);

    // FFN: W1 relu -> hid(hi/lo, aliased), W2 (+resid xb) -> xb in-place; LN2
    gemm_bf16<<<gff, 256, 0, stream>>>(xh, xl, Whb + 1048576, Wlb + 1048576, b1 + l*DFF, nullptr, nullptr, hidh, hidl, NB*LSEQ, DFF, DMODEL, 1);
    gemm_bf16<<<g512, 256, 0, stream>>>(hidh, hidl, Whb + 2097152, Wlb + 2097152, b2 + l*DMODEL, xb, xb, nullptr, nullptr, NB*LSEQ, DMODEL, DFF, 2);
    ln_k<<<NB * LSEQ, 256, 0, stream>>>(xb, g2 + l*DMODEL, be2 + l*DMODEL, xb, xh, xl, nullptr);
  }

  // final LN (*mark) -> tmp ; split-K fc
  ln_k<<<NB * LSEQ, 256, 0, stream>>>(xb, gF, bF, tmp, nullptr, nullptr, x_mark);
  fc_stage1<<<512, 256, 0, stream>>>(tmp, fcw, part);
  fc_stage2<<<1, 128, 0, stream>>>(part, fcb, out);
}

// Round 3
// 1858.093 us; speedup vs baseline: 2.0628x; 1.2445x over previous
//
#include <hip/hip_runtime.h>
#include <stdint.h>
#include <math.h>

// ---------------- problem constants ----------------
#define LSEQ   1024
#define DMODEL 512
#define NH     8
#define DH     64
#define DFF    2048
#define NB     8
#define NLAYER 3
#define UTOP   35
#define NCLS   16

typedef unsigned short u16;
typedef __attribute__((ext_vector_type(8))) short short8;
typedef __attribute__((ext_vector_type(4))) float f32x4;

// bf16 helpers (RNE)
__device__ __forceinline__ u16 f2bf(float f) {
  unsigned int u = __float_as_uint(f);
  unsigned int r = (u + 0x7fffu + ((u >> 16) & 1u)) >> 16;
  return (u16)r;
}
__device__ __forceinline__ float bf2f(u16 h) {
  return __uint_as_float(((unsigned int)h) << 16);
}

#define GLDS16(gsrc, ldst)                                                        \
  __builtin_amdgcn_global_load_lds(                                              \
      (const __attribute__((address_space(1))) void*)(gsrc),                     \
      (__attribute__((address_space(3))) void*)(ldst), 16, 0, 0)

// ---------------- threefry2x32 (exact JAX semantics) ----------------
__host__ __device__ __forceinline__ uint32_t rotl32(uint32_t x, int d) {
  return (x << d) | (x >> (32 - d));
}
__host__ __device__ inline void tf2x32(uint32_t k0, uint32_t k1,
                                       uint32_t c0, uint32_t c1,
                                       uint32_t& o0, uint32_t& o1) {
  uint32_t ks2 = k0 ^ k1 ^ 0x1BD11BDAu;
  uint32_t x0 = c0 + k0, x1 = c1 + k1;
#define TF_R4(a,b,c,d) \
  x0 += x1; x1 = rotl32(x1,(a)); x1 ^= x0; \
  x0 += x1; x1 = rotl32(x1,(b)); x1 ^= x0; \
  x0 += x1; x1 = rotl32(x1,(c)); x1 ^= x0; \
  x0 += x1; x1 = rotl32(x1,(d)); x1 ^= x0;
  TF_R4(13,15,26,6)   x0 += k1;  x1 += ks2 + 1u;
  TF_R4(17,29,16,24)  x0 += ks2; x1 += k0 + 2u;
  TF_R4(13,15,26,6)   x0 += k0;  x1 += k1 + 3u;
  TF_R4(17,29,16,24)  x0 += k1;  x1 += ks2 + 4u;
  TF_R4(13,15,26,6)   x0 += ks2; x1 += k0 + 5u;
#undef TF_R4
  o0 = x0; o1 = x1;
}

__global__ void __launch_bounds__(256) gen_idx_kernel(uint32_t k0, uint32_t k1,
                                                      int* idx) {
  int i = blockIdx.x * 256 + threadIdx.x;
  if (i >= LSEQ * UTOP) return;
  uint32_t a, b;
  tf2x32(k0, k1, 0u, (uint32_t)i, a, b);
  idx[i] = (int)((a ^ b) & (LSEQ - 1));
}

// ---------------- fp32 -> bf16 hi/lo split ----------------
__global__ void __launch_bounds__(256) cvt_split(const float* __restrict__ src,
                                                 u16* __restrict__ dh,
                                                 u16* __restrict__ dl, int n4) {
  int i = blockIdx.x * 256 + threadIdx.x;
  if (i >= n4) return;
  float4 v = *(const float4*)&src[i * 4];
  ushort4 h, l;
  h.x = f2bf(v.x); l.x = f2bf(v.x - bf2f(h.x));
  h.y = f2bf(v.y); l.y = f2bf(v.y - bf2f(h.y));
  h.z = f2bf(v.z); l.z = f2bf(v.z - bf2f(h.z));
  h.w = f2bf(v.w); l.w = f2bf(v.w - bf2f(h.w));
  *(ushort4*)&dh[i * 4] = h;
  *(ushort4*)&dl[i * 4] = l;
}

// ---------------- conv1d (circular pad 1) + PE, tiled ----------------
// block: 64 d x 32 l, loop over all 8 batches; w chunk + x rows in LDS.
__global__ void __launch_bounds__(256) conv_pe(const float* __restrict__ xe,
                                               const float* __restrict__ w,
                                               float* __restrict__ xout,
                                               u16* __restrict__ xh,
                                               u16* __restrict__ xl) {
  const int d0 = blockIdx.x * 64;     // 8 tiles
  const int l0 = blockIdx.y * 32;     // 32 tiles
  const int tid = threadIdx.x;
  const int dl = tid & 63;            // d_local
  const int lq = tid >> 6;            // 0..3, 8 l's each
  __shared__ float ws_[64][97];       // stride 97: consecutive d -> consecutive banks
  __shared__ float xs[32][37];        // [c][row], rows l0-1 .. l0+32

  for (int i = tid; i < 64 * 96; i += 256) {
    int dd = i / 96, cc = i - dd * 96;
    ws_[dd][cc] = w[(size_t)(d0 + dd) * 96 + cc];
  }

  // PE once per (l,d), reused across b
  const int d = d0 + dl;
  float div = expf((float)(d & ~1) * (-9.210340371976184f / 512.0f));
  float pe[8];
  #pragma unroll
  for (int j = 0; j < 8; ++j) {
    float arg = (float)(l0 + lq * 8 + j) * div;
    pe[j] = (d & 1) ? cosf(arg) : sinf(arg);
  }

  for (int b = 0; b < NB; ++b) {
    __syncthreads();
    for (int i = tid; i < 34 * 32; i += 256) {
      int r = i >> 5, c = i & 31;
      int row = (l0 - 1 + r + LSEQ) & (LSEQ - 1);
      xs[c][r] = xe[((size_t)b * LSEQ + row) * 32 + c];
    }
    __syncthreads();
    float acc[8] = {};
    #pragma unroll 4
    for (int c = 0; c < 32; ++c) {
      float w0 = ws_[dl][c * 3 + 0];
      float w1 = ws_[dl][c * 3 + 1];
      float w2 = ws_[dl][c * 3 + 2];
      float xv[10];
      #pragma unroll
      for (int r = 0; r < 10; ++r) xv[r] = xs[c][lq * 8 + r];
      #pragma unroll
      for (int j = 0; j < 8; ++j)
        acc[j] += xv[j] * w0 + xv[j + 1] * w1 + xv[j + 2] * w2;
    }
    #pragma unroll
    for (int j = 0; j < 8; ++j) {
      int l = l0 + lq * 8 + j;
      float v = acc[j] + pe[j];
      size_t o = ((size_t)b * LSEQ + l) * DMODEL + d;
      xout[o] = v;
      u16 h = f2bf(v);
      xh[o] = h;
      xl[o] = f2bf(v - bf2f(h));
    }
  }
}

// ---------------- split-bf16 MFMA GEMM, fused 3-product k-loop ----------------
// acc += Ah*Wh + Ah*Wl + Al*Wh  per k-tile (error ~4e-6 relative)
// mode: 1 = relu -> bf16 hi/lo out; 2 = +resid -> fp32 out;
//       3 = fused-QKV scatter to (B,H,L,dh) with N=1536 (bias_k/bias_v used)
__global__ void __launch_bounds__(256) gemm_bf16(
    const u16* __restrict__ Ah, const u16* __restrict__ Al,
    const u16* __restrict__ Wh, const u16* __restrict__ Wl,
    const float* __restrict__ bias, const float* __restrict__ bias_k,
    const float* __restrict__ bias_v, const float* __restrict__ resid,
    float* __restrict__ Cf, u16* __restrict__ Chi, u16* __restrict__ Clo,
    int M, int N, int K, int mode) {
  __shared__ u16 As[2][128 * 64];     // [0]=hi [1]=lo
  __shared__ u16 Bs[2][128 * 64];
  const int tid = threadIdx.x;
  const int lane = tid & 63, wv = tid >> 6;
  const int wm = wv >> 1, wn = wv & 1;
  const int m0 = blockIdx.y * 128, n0 = blockIdx.x * 128;
  const int lrow = lane >> 3;               // row within 8-row segment
  const int kgS = (lane & 7) ^ lrow;        // inverse-swizzled source k-group

  f32x4 acc[4][4];
  #pragma unroll
  for (int i = 0; i < 4; ++i)
    #pragma unroll
    for (int j = 0; j < 4; ++j) acc[i][j] = (f32x4){0.f, 0.f, 0.f, 0.f};

  for (int k0 = 0; k0 < K; k0 += 64) {
    #pragma unroll
    for (int r = 0; r < 4; ++r) {
      int seg = wv * 4 + r;                 // 0..15 (8 rows each)
      int row = seg * 8 + lrow;
      size_t ao = (size_t)(m0 + row) * K + k0 + kgS * 8;
      size_t bo = (size_t)(n0 + row) * K + k0 + kgS * 8;
      GLDS16(Ah + ao, &As[0][seg * 512]);
      GLDS16(Al + ao, &As[1][seg * 512]);
      GLDS16(Wh + bo, &Bs[0][seg * 512]);
      GLDS16(Wl + bo, &Bs[1][seg * 512]);
    }
    __syncthreads();
    #pragma unroll
    for (int kk = 0; kk < 2; ++kk) {
      int kg = kk * 4 + (lane >> 4);
      short8 afh[4], afl[4], bfh[4], bfl[4];
      #pragma unroll
      for (int mi = 0; mi < 4; ++mi) {
        int row = wm * 64 + mi * 16 + (lane & 15);
        int off = row * 64 + ((kg ^ (row & 7)) << 3);
        afh[mi] = *(const short8*)&As[0][off];
        afl[mi] = *(const short8*)&As[1][off];
      }
      #pragma unroll
      for (int ni = 0; ni < 4; ++ni) {
        int row = wn * 64 + ni * 16 + (lane & 15);
        int off = row * 64 + ((kg ^ (row & 7)) << 3);
        bfh[ni] = *(const short8*)&Bs[0][off];
        bfl[ni] = *(const short8*)&Bs[1][off];
      }
      #pragma unroll
      for (int mi = 0; mi < 4; ++mi)
        #pragma unroll
        for (int ni = 0; ni < 4; ++ni) {
          acc[mi][ni] = __builtin_amdgcn_mfma_f32_16x16x32_bf16(
              afh[mi], bfh[ni], acc[mi][ni], 0, 0, 0);
          acc[mi][ni] = __builtin_amdgcn_mfma_f32_16x16x32_bf16(
              afh[mi], bfl[ni], acc[mi][ni], 0, 0, 0);
          acc[mi][ni] = __builtin_amdgcn_mfma_f32_16x16x32_bf16(
              afl[mi], bfh[ni], acc[mi][ni], 0, 0, 0);
        }
    }
    __syncthreads();
  }

  // epilogue: C/D layout col = lane&15, row = (lane>>4)*4 + reg
  const int colb = n0 + wn * 64 + (lane & 15);
  const int rowb = m0 + wm * 64 + ((lane >> 4) << 2);
  #pragma unroll
  for (int mi = 0; mi < 4; ++mi) {
    #pragma unroll
    for (int ni = 0; ni < 4; ++ni) {
      int gcol = colb + ni * 16;
      float bv;
      if (mode == 3) {
        int mat = gcol >> 9, c = gcol & 511;
        bv = (mat == 0 ? bias : (mat == 1 ? bias_k : bias_v))[c];
      } else {
        bv = bias[gcol];
      }
      #pragma unroll
      for (int j = 0; j < 4; ++j) {
        int grow = rowb + mi * 16 + j;
        float v = acc[mi][ni][j] + bv;
        if (mode == 1) {
          size_t o = (size_t)grow * N + gcol;
          float vr = fmaxf(v, 0.f);
          u16 h = f2bf(vr);
          Chi[o] = h;
          Clo[o] = f2bf(vr - bf2f(h));
        } else if (mode == 2) {
          size_t o = (size_t)grow * N + gcol;
          Cf[o] = v + resid[o];
        } else {  // 3: fused QKV scatter; Cf = qb, kb = +NBLD, vb = +2*NBLD
          int mat = gcol >> 9, c = gcol & 511;
          Cf[(size_t)mat * (NB * LSEQ * DMODEL) +
             (size_t)(grow >> 10) * (NH * LSEQ * DH) +
             (size_t)(c >> 6) * (LSEQ * DH) +
             (size_t)(grow & (LSEQ - 1)) * DH + (c & (DH - 1))] = v;
        }
      }
    }
  }
}

// ---------------- M[b,h,l] = max_u q.k_samp - sum_u(q.k_samp)/L ----------------
// 4 rows per block (one per wave-group of 64)
__global__ void __launch_bounds__(256) sampled_m(const float* __restrict__ q,
                                                 const float* __restrict__ k,
                                                 const int* __restrict__ idx,
                                                 float* __restrict__ M) {
  int g = threadIdx.x >> 6, t = threadIdx.x & 63;
  int bhl = blockIdx.x * 4 + g;
  int l = bhl & (LSEQ - 1);
  int bh = bhl >> 10;
  __shared__ float qs[4][DH];
  qs[g][t] = q[(size_t)bhl * DH + t];
  __syncthreads();
  float vmax = -INFINITY, vsum = 0.f;
  if (t < UTOP) {
    int kr = idx[l * UTOP + t];
    const float4* kp = (const float4*)&k[((size_t)(bh << 10) + kr) * DH];
    const float4* q4 = (const float4*)qs[g];
    float d = 0.f;
    #pragma unroll
    for (int e = 0; e < DH / 4; ++e) {
      float4 kv = kp[e], qv = q4[e];
      d += qv.x * kv.x + qv.y * kv.y + qv.z * kv.z + qv.w * kv.w;
    }
    vmax = d; vsum = d;
  }
  #pragma unroll
  for (int off = 32; off; off >>= 1) {
    vmax = fmaxf(vmax, __shfl_down(vmax, off));
    vsum += __shfl_down(vsum, off);
  }
  if (t == 0) M[bhl] = vmax - vsum * (1.0f / (float)LSEQ);
}

// ---------------- iterative top-35 per (b,h) ----------------
__global__ void __launch_bounds__(256) topk35(const float* __restrict__ M,
                                              int* __restrict__ top) {
  int bh = blockIdx.x;
  int t = threadIdx.x;
  __shared__ float mv[LSEQ];
  __shared__ float rv[256];
  __shared__ int   ri[256];
  for (int i = t; i < LSEQ; i += 256) mv[i] = M[(size_t)bh * LSEQ + i];
  __syncthreads();
  for (int it = 0; it < UTOP; ++it) {
    float bestv = -INFINITY; int besti = 0x7fffffff;
    for (int i = t; i < LSEQ; i += 256) {
      float v = mv[i];
      if (v > bestv || (v == bestv && i < besti)) { bestv = v; besti = i; }
    }
    rv[t] = bestv; ri[t] = besti;
    __syncthreads();
    for (int s = 128; s; s >>= 1) {
      if (t < s) {
        float v2 = rv[t + s]; int i2 = ri[t + s];
        if (v2 > rv[t] || (v2 == rv[t] && i2 < ri[t])) { rv[t] = v2; ri[t] = i2; }
      }
      __syncthreads();
    }
    if (t == 0) { top[bh * UTOP + it] = ri[0]; mv[ri[0]] = -INFINITY; }
    __syncthreads();
  }
}

// ---------------- vmean[b,h,e] = mean_l v ----------------
__global__ void __launch_bounds__(64) vmean_k(const float* __restrict__ v,
                                              float* __restrict__ vm) {
  int bh = blockIdx.x, e = threadIdx.x;
  const float* vp = v + (size_t)bh * LSEQ * DH;
  float s = 0.f;
  for (int l = 0; l < LSEQ; ++l) s += vp[(size_t)l * DH + e];
  vm[bh * DH + e] = s * (1.0f / (float)LSEQ);
}

__global__ void __launch_bounds__(256) ctx_fill(const float* __restrict__ vm,
                                                float* __restrict__ ctx) {
  int i = blockIdx.x * 256 + threadIdx.x;
  int e = i & (DH - 1);
  int bh = i >> 16;
  ctx[i] = vm[bh * DH + e];
}

// ---------------- full attention for the 35 selected rows ----------------
__global__ void __launch_bounds__(256) attn_rows(const float* __restrict__ q,
                                                 const float* __restrict__ k,
                                                 const float* __restrict__ v,
                                                 const int* __restrict__ top,
                                                 float* __restrict__ ctx) {
  int bh = blockIdx.x / UTOP;
  int u  = blockIdx.x % UTOP;
  int t = threadIdx.x;
  __shared__ float qs[DH];
  __shared__ float sc[LSEQ];
  __shared__ float red[256];
  __shared__ float part[4][DH];
  int lrow = top[bh * UTOP + u];
  if (t < DH) qs[t] = q[((size_t)bh * LSEQ + lrow) * DH + t];
  __syncthreads();
  float lmax = -INFINITY;
  for (int kk = t; kk < LSEQ; kk += 256) {
    const float4* kp = (const float4*)&k[((size_t)bh * LSEQ + kk) * DH];
    const float4* q4 = (const float4*)qs;
    float d = 0.f;
    #pragma unroll
    for (int e = 0; e < DH / 4; ++e) {
      float4 kv = kp[e], qv = q4[e];
      d += qv.x * kv.x + qv.y * kv.y + qv.z * kv.z + qv.w * kv.w;
    }
    d *= 0.125f;
    sc[kk] = d;
    lmax = fmaxf(lmax, d);
  }
  red[t] = lmax; __syncthreads();
  for (int s = 128; s; s >>= 1) { if (t < s) red[t] = fmaxf(red[t], red[t + s]); __syncthreads(); }
  float mx = red[0];
  __syncthreads();
  float lsum = 0.f;
  for (int kk = t; kk < LSEQ; kk += 256) { float p = expf(sc[kk] - mx); sc[kk] = p; lsum += p; }
  red[t] = lsum; __syncthreads();
  for (int s = 128; s; s >>= 1) { if (t < s) red[t] += red[t + s]; __syncthreads(); }
  float inv = 1.0f / red[0];
  __syncthreads();
  int e = t & (DH - 1), c = t >> 6;
  float acc = 0.f;
  for (int kk = c * 256; kk < (c + 1) * 256; ++kk)
    acc += sc[kk] * v[((size_t)bh * LSEQ + kk) * DH + e];
  part[c][e] = acc; __syncthreads();
  if (t < DH) {
    float s4 = (part[0][t] + part[1][t] + part[2][t] + part[3][t]) * inv;
    ctx[((size_t)bh * LSEQ + lrow) * DH + t] = s4;
  }
}

// ---------------- layernorm over D=512; optional bf16 hi/lo out, optional mark ----
__global__ void __launch_bounds__(256) ln_k(const float* __restrict__ in,
                                            const float* __restrict__ g,
                                            const float* __restrict__ be,
                                            float* __restrict__ out,
                                            u16* __restrict__ oh,
                                            u16* __restrict__ ol,
                                            const float* __restrict__ mark) {
  int row = blockIdx.x, t = threadIdx.x;
  const float* p = in + (size_t)row * DMODEL;
  float x0 = p[t], x1 = p[t + 256];
  __shared__ float red[256];
  red[t] = x0 + x1; __syncthreads();
  for (int s = 128; s; s >>= 1) { if (t < s) red[t] += red[t + s]; __syncthreads(); }
  float mean = red[0] * (1.0f / DMODEL);
  __syncthreads();
  float d0 = x0 - mean, d1 = x1 - mean;
  red[t] = d0 * d0 + d1 * d1; __syncthreads();
  for (int s = 128; s; s >>= 1) { if (t < s) red[t] += red[t + s]; __syncthreads(); }
  float rstd = 1.0f / sqrtf(red[0] * (1.0f / DMODEL) + 1e-5f);
  float v0 = d0 * rstd * g[t] + be[t];
  float v1 = d1 * rstd * g[t + 256] + be[t + 256];
  if (mark) { float mk = mark[row]; v0 *= mk; v1 *= mk; }
  size_t o0 = (size_t)row * DMODEL + t, o1 = o0 + 256;
  out[o0] = v0; out[o1] = v1;
  if (oh) {
    u16 h0 = f2bf(v0), h1 = f2bf(v1);
    oh[o0] = h0; ol[o0] = f2bf(v0 - bf2f(h0));
    oh[o1] = h1; ol[o1] = f2bf(v1 - bf2f(h1));
  }
}

// ---------------- final fc: split-K two-stage ----------------
__global__ void __launch_bounds__(256) fc_stage1(const float* __restrict__ y,
                                                 const float* __restrict__ fw,
                                                 float* __restrict__ part) {
  int blk = blockIdx.x;
  int k0 = blk * 1024;
  int tid = threadIdx.x;
  __shared__ float ys[NB][1024];
  #pragma unroll
  for (int b = 0; b < NB; ++b)
    *(float4*)&ys[b][tid * 4] = *(const float4*)&y[(size_t)b * (LSEQ * DMODEL) + k0 + tid * 4];
  __syncthreads();
  int c = tid & 15, ks = tid >> 4;
  float acc[NB] = {};
  const float* wp = fw + (size_t)c * (LSEQ * DMODEL) + k0 + ks * 64;
  for (int j = 0; j < 16; ++j) {
    int jj = (j + ks) & 15;
    float4 w4 = *(const float4*)&wp[jj * 4];
    #pragma unroll
    for (int b = 0; b < NB; ++b) {
      float4 yv = *(const float4*)&ys[b][ks * 64 + jj * 4];
      acc[b] += yv.x * w4.x + yv.y * w4.y + yv.z * w4.z + yv.w * w4.w;
    }
  }
  __shared__ float rs[16][128];
  #pragma unroll
  for (int b = 0; b < NB; ++b) rs[ks][b * 16 + c] = acc[b];
  __syncthreads();
  if (tid < 128) {
    float s = 0.f;
    #pragma unroll
    for (int i = 0; i < 16; ++i) s += rs[i][tid];
    part[(size_t)tid * 512 + blk] = s;
  }
}

__global__ void __launch_bounds__(128) fc_stage2(const float* __restrict__ part,
                                                 const float* __restrict__ fb,
                                                 float* __restrict__ out) {
  int bc = threadIdx.x;
  float s = 0.f;
  for (int i = 0; i < 512; ++i) s += part[(size_t)bc * 512 + i];
  out[bc] = s + fb[bc & 15];
}

// ---------------- host launch ----------------
extern "C" void kernel_launch(void* const* d_in, const int* in_sizes, int n_in,
                              void* d_out, int out_size, void* d_ws, size_t ws_size,
                              hipStream_t stream) {
  (void)in_sizes; (void)n_in; (void)out_size; (void)ws_size;
  const float* x_enc  = (const float*)d_in[0];
  const float* x_mark = (const float*)d_in[1];
  const float* conv_w = (const float*)d_in[2];
  const float* Wq = (const float*)d_in[3];
  const float* bq = (const float*)d_in[4];
  const float* Wk = (const float*)d_in[5];
  const float* bk = (const float*)d_in[6];
  const float* Wv = (const float*)d_in[7];
  const float* bv = (const float*)d_in[8];
  const float* Wo = (const float*)d_in[9];
  const float* bo = (const float*)d_in[10];
  const float* W1 = (const float*)d_in[11];
  const float* b1 = (const float*)d_in[12];
  const float* W2 = (const float*)d_in[13];
  const float* b2 = (const float*)d_in[14];
  const float* g1 = (const float*)d_in[15];
  const float* be1= (const float*)d_in[16];
  const float* g2 = (const float*)d_in[17];
  const float* be2= (const float*)d_in[18];
  const float* gF = (const float*)d_in[19];
  const float* bF = (const float*)d_in[20];
  const float* fcw= (const float*)d_in[21];
  const float* fcb= (const float*)d_in[22];
  float* out = (float*)d_out;

  const size_t NBLD = (size_t)NB * LSEQ * DMODEL;       // 4,194,304
  float* ws  = (float*)d_ws;
  float* xb  = ws;
  float* tmp = xb  + NBLD;
  float* qb  = tmp + NBLD;       // qb,kb,vb contiguous (fused-QKV scatter relies on this)
  float* kb  = qb  + NBLD;
  float* vb  = kb  + NBLD;
  u16*  xh   = (u16*)(vb + NBLD);
  u16*  xl   = xh + NBLD;
  u16*  ch   = xl + NBLD;        // ctx hi
  u16*  cl   = ch + NBLD;        // ctx lo
  u16*  Whb  = cl + NBLD;        // per-layer weights hi (3,145,728 u16)
  u16*  Wlb  = Whb + 3145728;
  float* Mb  = (float*)(Wlb + 3145728);
  float* vm  = Mb + (size_t)NB * NH * LSEQ;
  float* part= vm + NB * NH * DH;
  int* idxb  = (int*)(part + 512 * 128);
  int* topb  = idxb + LSEQ * UTOP;
  // FFN hidden bf16 hi/lo aliased into dead fp32 regions:
  u16* hidh  = (u16*)kb;
  u16* hidl  = (u16*)tmp;

  {
    dim3 gc(8, 32);
    conv_pe<<<gc, 256, 0, stream>>>(x_enc, conv_w, xb, xh, xl);
  }

  dim3 gqkv(12, 64);   // fused QKV: N=1536
  dim3 g512(4, 64);    // N=512
  dim3 gff (16, 64);   // N=2048

  for (int l = 0; l < NLAYER; ++l) {
    cvt_split<<<262144/1024 + 1, 256, 0, stream>>>(Wq + (size_t)l*262144, Whb + 0,       Wlb + 0,       262144/4);
    cvt_split<<<262144/1024 + 1, 256, 0, stream>>>(Wk + (size_t)l*262144, Whb + 262144,  Wlb + 262144,  262144/4);
    cvt_split<<<262144/1024 + 1, 256, 0, stream>>>(Wv + (size_t)l*262144, Whb + 524288,  Wlb + 524288,  262144/4);
    cvt_split<<<262144/1024 + 1, 256, 0, stream>>>(Wo + (size_t)l*262144, Whb + 786432,  Wlb + 786432,  262144/4);
    cvt_split<<<1048576/1024 + 1, 256, 0, stream>>>(W1 + (size_t)l*1048576, Whb + 1048576, Wlb + 1048576, 1048576/4);
    cvt_split<<<1048576/1024 + 1, 256, 0, stream>>>(W2 + (size_t)l*1048576, Whb + 2097152, Wlb + 2097152, 1048576/4);

    // fused QKV (mode 3): weights rows 0..511=Wq, 512..1023=Wk, 1024..1535=Wv
    gemm_bf16<<<gqkv, 256, 0, stream>>>(xh, xl, Whb, Wlb,
                                        bq + l*DMODEL, bk + l*DMODEL, bv + l*DMODEL,
                                        nullptr, qb, nullptr, nullptr,
                                        NB*LSEQ, 1536, DMODEL, 3);

    // prob-attention
    uint32_t lk0, lk1, k2_0, k2_1;
    tf2x32(0u, 42u, 0u, (uint32_t)l, lk0, lk1);
    tf2x32(lk0, lk1, 0u, 1u, k2_0, k2_1);
    gen_idx_kernel<<<140, 256, 0, stream>>>(k2_0, k2_1, idxb);
    sampled_m<<<NB * NH * LSEQ / 4, 256, 0, stream>>>(qb, kb, idxb, Mb);
    topk35<<<NB * NH, 256, 0, stream>>>(Mb, topb);
    vmean_k<<<NB * NH, 64, 0, stream>>>(vb, vm);
    ctx_fill<<<(NB * NH * LSEQ * DH) / 256, 256, 0, stream>>>(vm, tmp);
    attn_rows<<<NB * NH * UTOP, 256, 0, stream>>>(qb, kb, vb, topb, tmp);

    // ctx -> bf16 hi/lo
    cvt_split<<<NBLD / 1024, 256, 0, stream>>>(tmp, ch, cl, NBLD / 4);

    // Wo GEMM (+resid xb) -> qb ; LN1 -> xb (+hi/lo)
    gemm_bf16<<<g512, 256, 0, stream>>>(ch, cl, Whb + 786432, Wlb + 786432,
                                        bo + l*DMODEL, nullptr, nullptr,
                                        xb, qb, nullptr, nullptr,
                                        NB*LSEQ, DMODEL, DMODEL, 2);
    ln_k<<<NB * LSEQ, 256, 0, stream>>>(qb, g1 + l*DMODEL, be1 + l*DMODEL, xb, xh, xl, nullptr);

    // FFN
    gemm_bf16<<<gff, 256, 0, stream>>>(xh, xl, Whb + 1048576, Wlb + 1048576,
                                       b1 + l*DFF, nullptr, nullptr,
                                       nullptr, nullptr, hidh, hidl,
                                       NB*LSEQ, DFF, DMODEL, 1);
    gemm_bf16<<<g512, 256, 0, stream>>>(hidh, hidl, Whb + 2097152, Wlb + 2097152,
                                        b2 + l*DMODEL, nullptr, nullptr,
                                        xb, xb, nullptr, nullptr,
                                        NB*LSEQ, DMODEL, DFF, 2);
    ln_k<<<NB * LSEQ, 256, 0, stream>>>(xb, g2 + l*DMODEL, be2 + l*DMODEL, xb, xh, xl, nullptr);
  }

  ln_k<<<NB * LSEQ, 256, 0, stream>>>(xb, gF, bF, tmp, nullptr, nullptr, x_mark);
  fc_stage1<<<512, 256, 0, stream>>>(tmp, fcw, part);
  fc_stage2<<<1, 128, 0, stream>>>(part, fcb, out);
}

// Round 4
// 1539.471 us; speedup vs baseline: 2.4897x; 1.2070x over previous
//
#include <hip/hip_runtime.h>
#include <stdint.h>
#include <math.h>

// ---------------- problem constants ----------------
#define LSEQ   1024
#define DMODEL 512
#define NH     8
#define DH     64
#define DFF    2048
#define NB     8
#define NLAYER 3
#define UTOP   35
#define NCLS   16

typedef unsigned short u16;
typedef __attribute__((ext_vector_type(8))) short short8;
typedef __attribute__((ext_vector_type(4))) float f32x4;

// bf16 helpers (RNE)
__device__ __forceinline__ u16 f2bf(float f) {
  unsigned int u = __float_as_uint(f);
  unsigned int r = (u + 0x7fffu + ((u >> 16) & 1u)) >> 16;
  return (u16)r;
}
__device__ __forceinline__ float bf2f(u16 h) {
  return __uint_as_float(((unsigned int)h) << 16);
}

#define GLDS16(gsrc, ldst)                                                        \
  __builtin_amdgcn_global_load_lds(                                              \
      (const __attribute__((address_space(1))) void*)(gsrc),                     \
      (__attribute__((address_space(3))) void*)(ldst), 16, 0, 0)

// ---------------- threefry2x32 (exact JAX semantics) ----------------
__host__ __device__ __forceinline__ uint32_t rotl32(uint32_t x, int d) {
  return (x << d) | (x >> (32 - d));
}
__host__ __device__ inline void tf2x32(uint32_t k0, uint32_t k1,
                                       uint32_t c0, uint32_t c1,
                                       uint32_t& o0, uint32_t& o1) {
  uint32_t ks2 = k0 ^ k1 ^ 0x1BD11BDAu;
  uint32_t x0 = c0 + k0, x1 = c1 + k1;
#define TF_R4(a,b,c,d) \
  x0 += x1; x1 = rotl32(x1,(a)); x1 ^= x0; \
  x0 += x1; x1 = rotl32(x1,(b)); x1 ^= x0; \
  x0 += x1; x1 = rotl32(x1,(c)); x1 ^= x0; \
  x0 += x1; x1 = rotl32(x1,(d)); x1 ^= x0;
  TF_R4(13,15,26,6)   x0 += k1;  x1 += ks2 + 1u;
  TF_R4(17,29,16,24)  x0 += ks2; x1 += k0 + 2u;
  TF_R4(13,15,26,6)   x0 += k0;  x1 += k1 + 3u;
  TF_R4(17,29,16,24)  x0 += k1;  x1 += ks2 + 4u;
  TF_R4(13,15,26,6)   x0 += ks2; x1 += k0 + 5u;
#undef TF_R4
  o0 = x0; o1 = x1;
}

__global__ void __launch_bounds__(256) gen_idx_kernel(uint32_t k0, uint32_t k1,
                                                      int* idx) {
  int i = blockIdx.x * 256 + threadIdx.x;
  if (i >= LSEQ * UTOP) return;
  uint32_t a, b;
  tf2x32(k0, k1, 0u, (uint32_t)i, a, b);
  idx[i] = (int)((a ^ b) & (LSEQ - 1));
}

// ---------------- fp32 -> bf16 hi/lo split ----------------
__global__ void __launch_bounds__(256) cvt_split(const float* __restrict__ src,
                                                 u16* __restrict__ dh,
                                                 u16* __restrict__ dl, int n4) {
  int i = blockIdx.x * 256 + threadIdx.x;
  if (i >= n4) return;
  float4 v = *(const float4*)&src[i * 4];
  ushort4 h, l;
  h.x = f2bf(v.x); l.x = f2bf(v.x - bf2f(h.x));
  h.y = f2bf(v.y); l.y = f2bf(v.y - bf2f(h.y));
  h.z = f2bf(v.z); l.z = f2bf(v.z - bf2f(h.z));
  h.w = f2bf(v.w); l.w = f2bf(v.w - bf2f(h.w));
  *(ushort4*)&dh[i * 4] = h;
  *(ushort4*)&dl[i * 4] = l;
}

// ---------------- conv1d (circular pad 1) + PE, tiled ----------------
__global__ void __launch_bounds__(256) conv_pe(const float* __restrict__ xe,
                                               const float* __restrict__ w,
                                               float* __restrict__ xout,
                                               u16* __restrict__ xh,
                                               u16* __restrict__ xl) {
  const int d0 = blockIdx.x * 64;
  const int l0 = blockIdx.y * 32;
  const int tid = threadIdx.x;
  const int dl = tid & 63;
  const int lq = tid >> 6;
  __shared__ float ws_[64][97];
  __shared__ float xs[32][37];

  for (int i = tid; i < 64 * 96; i += 256) {
    int dd = i / 96, cc = i - dd * 96;
    ws_[dd][cc] = w[(size_t)(d0 + dd) * 96 + cc];
  }

  const int d = d0 + dl;
  float div = expf((float)(d & ~1) * (-9.210340371976184f / 512.0f));
  float pe[8];
  #pragma unroll
  for (int j = 0; j < 8; ++j) {
    float arg = (float)(l0 + lq * 8 + j) * div;
    pe[j] = (d & 1) ? cosf(arg) : sinf(arg);
  }

  for (int b = 0; b < NB; ++b) {
    __syncthreads();
    for (int i = tid; i < 34 * 32; i += 256) {
      int r = i >> 5, c = i & 31;
      int row = (l0 - 1 + r + LSEQ) & (LSEQ - 1);
      xs[c][r] = xe[((size_t)b * LSEQ + row) * 32 + c];
    }
    __syncthreads();
    float acc[8] = {};
    #pragma unroll 4
    for (int c = 0; c < 32; ++c) {
      float w0 = ws_[dl][c * 3 + 0];
      float w1 = ws_[dl][c * 3 + 1];
      float w2 = ws_[dl][c * 3 + 2];
      float xv[10];
      #pragma unroll
      for (int r = 0; r < 10; ++r) xv[r] = xs[c][lq * 8 + r];
      #pragma unroll
      for (int j = 0; j < 8; ++j)
        acc[j] += xv[j] * w0 + xv[j + 1] * w1 + xv[j + 2] * w2;
    }
    #pragma unroll
    for (int j = 0; j < 8; ++j) {
      int l = l0 + lq * 8 + j;
      float v = acc[j] + pe[j];
      size_t o = ((size_t)b * LSEQ + l) * DMODEL + d;
      xout[o] = v;
      u16 h = f2bf(v);
      xh[o] = h;
      xl[o] = f2bf(v - bf2f(h));
    }
  }
}

// ---------------- split-bf16 MFMA GEMM, fused 3-product k-loop ----------------
__global__ void __launch_bounds__(256) gemm_bf16(
    const u16* __restrict__ Ah, const u16* __restrict__ Al,
    const u16* __restrict__ Wh, const u16* __restrict__ Wl,
    const float* __restrict__ bias, const float* __restrict__ bias_k,
    const float* __restrict__ bias_v, const float* __restrict__ resid,
    float* __restrict__ Cf, u16* __restrict__ Chi, u16* __restrict__ Clo,
    int M, int N, int K, int mode) {
  __shared__ u16 As[2][128 * 64];
  __shared__ u16 Bs[2][128 * 64];
  const int tid = threadIdx.x;
  const int lane = tid & 63, wv = tid >> 6;
  const int wm = wv >> 1, wn = wv & 1;
  const int m0 = blockIdx.y * 128, n0 = blockIdx.x * 128;
  const int lrow = lane >> 3;
  const int kgS = (lane & 7) ^ lrow;

  f32x4 acc[4][4];
  #pragma unroll
  for (int i = 0; i < 4; ++i)
    #pragma unroll
    for (int j = 0; j < 4; ++j) acc[i][j] = (f32x4){0.f, 0.f, 0.f, 0.f};

  for (int k0 = 0; k0 < K; k0 += 64) {
    #pragma unroll
    for (int r = 0; r < 4; ++r) {
      int seg = wv * 4 + r;
      int row = seg * 8 + lrow;
      size_t ao = (size_t)(m0 + row) * K + k0 + kgS * 8;
      size_t bo = (size_t)(n0 + row) * K + k0 + kgS * 8;
      GLDS16(Ah + ao, &As[0][seg * 512]);
      GLDS16(Al + ao, &As[1][seg * 512]);
      GLDS16(Wh + bo, &Bs[0][seg * 512]);
      GLDS16(Wl + bo, &Bs[1][seg * 512]);
    }
    __syncthreads();
    #pragma unroll
    for (int kk = 0; kk < 2; ++kk) {
      int kg = kk * 4 + (lane >> 4);
      short8 afh[4], afl[4], bfh[4], bfl[4];
      #pragma unroll
      for (int mi = 0; mi < 4; ++mi) {
        int row = wm * 64 + mi * 16 + (lane & 15);
        int off = row * 64 + ((kg ^ (row & 7)) << 3);
        afh[mi] = *(const short8*)&As[0][off];
        afl[mi] = *(const short8*)&As[1][off];
      }
      #pragma unroll
      for (int ni = 0; ni < 4; ++ni) {
        int row = wn * 64 + ni * 16 + (lane & 15);
        int off = row * 64 + ((kg ^ (row & 7)) << 3);
        bfh[ni] = *(const short8*)&Bs[0][off];
        bfl[ni] = *(const short8*)&Bs[1][off];
      }
      #pragma unroll
      for (int mi = 0; mi < 4; ++mi)
        #pragma unroll
        for (int ni = 0; ni < 4; ++ni) {
          acc[mi][ni] = __builtin_amdgcn_mfma_f32_16x16x32_bf16(
              afh[mi], bfh[ni], acc[mi][ni], 0, 0, 0);
          acc[mi][ni] = __builtin_amdgcn_mfma_f32_16x16x32_bf16(
              afh[mi], bfl[ni], acc[mi][ni], 0, 0, 0);
          acc[mi][ni] = __builtin_amdgcn_mfma_f32_16x16x32_bf16(
              afl[mi], bfh[ni], acc[mi][ni], 0, 0, 0);
        }
    }
    __syncthreads();
  }

  const int colb = n0 + wn * 64 + (lane & 15);
  const int rowb = m0 + wm * 64 + ((lane >> 4) << 2);
  #pragma unroll
  for (int mi = 0; mi < 4; ++mi) {
    #pragma unroll
    for (int ni = 0; ni < 4; ++ni) {
      int gcol = colb + ni * 16;
      float bv;
      if (mode == 3) {
        int mat = gcol >> 9, c = gcol & 511;
        bv = (mat == 0 ? bias : (mat == 1 ? bias_k : bias_v))[c];
      } else {
        bv = bias[gcol];
      }
      #pragma unroll
      for (int j = 0; j < 4; ++j) {
        int grow = rowb + mi * 16 + j;
        float v = acc[mi][ni][j] + bv;
        if (mode == 1) {
          size_t o = (size_t)grow * N + gcol;
          float vr = fmaxf(v, 0.f);
          u16 h = f2bf(vr);
          Chi[o] = h;
          Clo[o] = f2bf(vr - bf2f(h));
        } else if (mode == 2) {
          size_t o = (size_t)grow * N + gcol;
          Cf[o] = v + resid[o];
        } else {
          int mat = gcol >> 9, c = gcol & 511;
          Cf[(size_t)mat * (NB * LSEQ * DMODEL) +
             (size_t)(grow >> 10) * (NH * LSEQ * DH) +
             (size_t)(c >> 6) * (LSEQ * DH) +
             (size_t)(grow & (LSEQ - 1)) * DH + (c & (DH - 1))] = v;
        }
      }
    }
  }
}

// ---------------- M[b,h,l] = max_u q.k_samp - sum_u(q.k_samp)/L ----------------
__global__ void __launch_bounds__(256) sampled_m(const float* __restrict__ q,
                                                 const float* __restrict__ k,
                                                 const int* __restrict__ idx,
                                                 float* __restrict__ M) {
  int g = threadIdx.x >> 6, t = threadIdx.x & 63;
  int bhl = blockIdx.x * 4 + g;
  int l = bhl & (LSEQ - 1);
  int bh = bhl >> 10;
  __shared__ float qs[4][DH];
  qs[g][t] = q[(size_t)bhl * DH + t];
  __syncthreads();
  float vmax = -INFINITY, vsum = 0.f;
  if (t < UTOP) {
    int kr = idx[l * UTOP + t];
    const float4* kp = (const float4*)&k[((size_t)(bh << 10) + kr) * DH];
    const float4* q4 = (const float4*)qs[g];
    float d = 0.f;
    #pragma unroll
    for (int e = 0; e < DH / 4; ++e) {
      float4 kv = kp[e], qv = q4[e];
      d += qv.x * kv.x + qv.y * kv.y + qv.z * kv.z + qv.w * kv.w;
    }
    vmax = d; vsum = d;
  }
  #pragma unroll
  for (int off = 32; off; off >>= 1) {
    vmax = fmaxf(vmax, __shfl_down(vmax, off));
    vsum += __shfl_down(vsum, off);
  }
  if (t == 0) M[bhl] = vmax - vsum * (1.0f / (float)LSEQ);
}

// ---------------- iterative top-35 per (b,h) ----------------
__global__ void __launch_bounds__(256) topk35(const float* __restrict__ M,
                                              int* __restrict__ top) {
  int bh = blockIdx.x;
  int t = threadIdx.x;
  __shared__ float mv[LSEQ];
  __shared__ float rv[256];
  __shared__ int   ri[256];
  for (int i = t; i < LSEQ; i += 256) mv[i] = M[(size_t)bh * LSEQ + i];
  __syncthreads();
  for (int it = 0; it < UTOP; ++it) {
    float bestv = -INFINITY; int besti = 0x7fffffff;
    for (int i = t; i < LSEQ; i += 256) {
      float v = mv[i];
      if (v > bestv || (v == bestv && i < besti)) { bestv = v; besti = i; }
    }
    rv[t] = bestv; ri[t] = besti;
    __syncthreads();
    for (int s = 128; s; s >>= 1) {
      if (t < s) {
        float v2 = rv[t + s]; int i2 = ri[t + s];
        if (v2 > rv[t] || (v2 == rv[t] && i2 < ri[t])) { rv[t] = v2; ri[t] = i2; }
      }
      __syncthreads();
    }
    if (t == 0) { top[bh * UTOP + it] = ri[0]; mv[ri[0]] = -INFINITY; }
    __syncthreads();
  }
}

// ---------------- vmean[b,h,e] = mean_l v ----------------
__global__ void __launch_bounds__(256) vmean_k(const float* __restrict__ v,
                                               float* __restrict__ vm) {
  int bh = blockIdx.x, t = threadIdx.x;
  int e = t & 63, c = t >> 6;
  float s = 0.f;
  for (int l = c * 256; l < (c + 1) * 256; ++l)
    s += v[((size_t)bh * LSEQ + l) * DH + e];
  __shared__ float pr[4][64];
  pr[c][e] = s; __syncthreads();
  if (t < 64)
    vm[bh * DH + t] = (pr[0][t] + pr[1][t] + pr[2][t] + pr[3][t]) * (1.0f / (float)LSEQ);
}

// ---------------- ctx = vmean broadcast, written as bf16 hi/lo ----------------
__global__ void __launch_bounds__(256) ctx_fillb(const float* __restrict__ vm,
                                                 u16* __restrict__ ch,
                                                 u16* __restrict__ cl) {
  int i4 = (blockIdx.x * 256 + threadIdx.x) * 4;   // over B*H*L*DH
  int e = i4 & (DH - 1);
  int bh = i4 >> 16;
  float4 v = *(const float4*)&vm[bh * DH + e];
  ushort4 h, l;
  h.x = f2bf(v.x); l.x = f2bf(v.x - bf2f(h.x));
  h.y = f2bf(v.y); l.y = f2bf(v.y - bf2f(h.y));
  h.z = f2bf(v.z); l.z = f2bf(v.z - bf2f(h.z));
  h.w = f2bf(v.w); l.w = f2bf(v.w - bf2f(h.w));
  *(ushort4*)&ch[i4] = h;
  *(ushort4*)&cl[i4] = l;
}

// ---------------- attention for 5 selected rows per block ----------------
// grid = 448: bid -> (bh via XCD swizzle, u-chunk). All 7 u-chunks of a bh
// share bid%8 -> same XCD -> K/V panels stay in that XCD's L2.
__global__ void __launch_bounds__(256) attn_rows(const float* __restrict__ q,
                                                 const float* __restrict__ k,
                                                 const float* __restrict__ v,
                                                 const int* __restrict__ top,
                                                 u16* __restrict__ ch,
                                                 u16* __restrict__ cl) {
  const int bid = blockIdx.x;
  const int c6 = bid & 63, uc = bid >> 6;           // uc = 0..6
  const int bh = ((c6 & 7) << 3) | (c6 >> 3);       // bijective, bid%8 fixed per bh
  const int t = threadIdx.x;
  const int lane = t & 63, wvi = t >> 6;
  __shared__ float qs[5][DH];
  __shared__ float sc[5][LSEQ];
  __shared__ float red[32];
  __shared__ float part[4][5][DH];
  __shared__ float mxs[5], invs[5];
  int rows[5];
  #pragma unroll
  for (int i = 0; i < 5; ++i) rows[i] = top[bh * UTOP + uc * 5 + i];
  for (int i = t; i < 5 * DH; i += 256) {
    int u = i >> 6, e = i & 63;
    qs[u][e] = q[((size_t)bh * LSEQ + rows[u]) * DH + e];
  }
  __syncthreads();

  // pass 1: scores
  float mloc[5] = {-INFINITY, -INFINITY, -INFINITY, -INFINITY, -INFINITY};
  for (int kk = t; kk < LSEQ; kk += 256) {
    float4 kr[16];
    const float4* kp = (const float4*)&k[((size_t)bh * LSEQ + kk) * DH];
    #pragma unroll
    for (int e = 0; e < 16; ++e) kr[e] = kp[e];
    #pragma unroll
    for (int u = 0; u < 5; ++u) {
      const float4* q4 = (const float4*)qs[u];
      float d = 0.f;
      #pragma unroll
      for (int e = 0; e < 16; ++e) {
        float4 qv = q4[e];
        d += qv.x * kr[e].x + qv.y * kr[e].y + qv.z * kr[e].z + qv.w * kr[e].w;
      }
      d *= 0.125f;
      sc[u][kk] = d;
      mloc[u] = fmaxf(mloc[u], d);
    }
  }
  #pragma unroll
  for (int u = 0; u < 5; ++u) {
    float m = mloc[u];
    #pragma unroll
    for (int off = 32; off; off >>= 1) m = fmaxf(m, __shfl_down(m, off));
    if (lane == 0) red[u * 4 + wvi] = m;
  }
  __syncthreads();
  if (t < 5)
    mxs[t] = fmaxf(fmaxf(red[t * 4], red[t * 4 + 1]),
                   fmaxf(red[t * 4 + 2], red[t * 4 + 3]));
  __syncthreads();

  // pass 2: exp + sum
  float sloc[5] = {};
  for (int kk = t; kk < LSEQ; kk += 256) {
    #pragma unroll
    for (int u = 0; u < 5; ++u) {
      float p = expf(sc[u][kk] - mxs[u]);
      sc[u][kk] = p;
      sloc[u] += p;
    }
  }
  #pragma unroll
  for (int u = 0; u < 5; ++u) {
    float s = sloc[u];
    #pragma unroll
    for (int off = 32; off; off >>= 1) s += __shfl_down(s, off);
    if (lane == 0) red[u * 4 + wvi] = s;
  }
  __syncthreads();
  if (t < 5)
    invs[t] = 1.0f / (red[t * 4] + red[t * 4 + 1] + red[t * 4 + 2] + red[t * 4 + 3]);
  __syncthreads();

  // pass 3: PV
  int e = t & 63, cq = t >> 6;
  float acc[5] = {};
  for (int kk = cq * 256; kk < (cq + 1) * 256; ++kk) {
    float vv = v[((size_t)bh * LSEQ + kk) * DH + e];
    #pragma unroll
    for (int u = 0; u < 5; ++u) acc[u] += sc[u][kk] * vv;
  }
  #pragma unroll
  for (int u = 0; u < 5; ++u) part[cq][u][e] = acc[u];
  __syncthreads();
  for (int i = t; i < 5 * DH; i += 256) {
    int u = i >> 6, ee = i & 63;
    float s = (part[0][u][ee] + part[1][u][ee] + part[2][u][ee] + part[3][u][ee]) * invs[u];
    size_t o = ((size_t)bh * LSEQ + rows[u]) * DH + ee;
    u16 h = f2bf(s);
    ch[o] = h;
    cl[o] = f2bf(s - bf2f(h));
  }
}

// ---------------- layernorm over D=512 ----------------
__global__ void __launch_bounds__(256) ln_k(const float* __restrict__ in,
                                            const float* __restrict__ g,
                                            const float* __restrict__ be,
                                            float* __restrict__ out,
                                            u16* __restrict__ oh,
                                            u16* __restrict__ ol,
                                            const float* __restrict__ mark) {
  int row = blockIdx.x, t = threadIdx.x;
  const float* p = in + (size_t)row * DMODEL;
  float x0 = p[t], x1 = p[t + 256];
  __shared__ float red[256];
  red[t] = x0 + x1; __syncthreads();
  for (int s = 128; s; s >>= 1) { if (t < s) red[t] += red[t + s]; __syncthreads(); }
  float mean = red[0] * (1.0f / DMODEL);
  __syncthreads();
  float d0 = x0 - mean, d1 = x1 - mean;
  red[t] = d0 * d0 + d1 * d1; __syncthreads();
  for (int s = 128; s; s >>= 1) { if (t < s) red[t] += red[t + s]; __syncthreads(); }
  float rstd = 1.0f / sqrtf(red[0] * (1.0f / DMODEL) + 1e-5f);
  float v0 = d0 * rstd * g[t] + be[t];
  float v1 = d1 * rstd * g[t + 256] + be[t + 256];
  if (mark) { float mk = mark[row]; v0 *= mk; v1 *= mk; }
  size_t o0 = (size_t)row * DMODEL + t, o1 = o0 + 256;
  out[o0] = v0; out[o1] = v1;
  if (oh) {
    u16 h0 = f2bf(v0), h1 = f2bf(v1);
    oh[o0] = h0; ol[o0] = f2bf(v0 - bf2f(h0));
    oh[o1] = h1; ol[o1] = f2bf(v1 - bf2f(h1));
  }
}

// ---------------- final fc: split-K two-stage ----------------
__global__ void __launch_bounds__(256) fc_stage1(const float* __restrict__ y,
                                                 const float* __restrict__ fw,
                                                 float* __restrict__ part) {
  int blk = blockIdx.x;
  int k0 = blk * 1024;
  int tid = threadIdx.x;
  __shared__ float ys[NB][1024];
  #pragma unroll
  for (int b = 0; b < NB; ++b)
    *(float4*)&ys[b][tid * 4] = *(const float4*)&y[(size_t)b * (LSEQ * DMODEL) + k0 + tid * 4];
  __syncthreads();
  int c = tid & 15, ks = tid >> 4;
  float acc[NB] = {};
  const float* wp = fw + (size_t)c * (LSEQ * DMODEL) + k0 + ks * 64;
  for (int j = 0; j < 16; ++j) {
    int jj = (j + ks) & 15;
    float4 w4 = *(const float4*)&wp[jj * 4];
    #pragma unroll
    for (int b = 0; b < NB; ++b) {
      float4 yv = *(const float4*)&ys[b][ks * 64 + jj * 4];
      acc[b] += yv.x * w4.x + yv.y * w4.y + yv.z * w4.z + yv.w * w4.w;
    }
  }
  __shared__ float rs[16][128];
  #pragma unroll
  for (int b = 0; b < NB; ++b) rs[ks][b * 16 + c] = acc[b];
  __syncthreads();
  if (tid < 128) {
    float s = 0.f;
    #pragma unroll
    for (int i = 0; i < 16; ++i) s += rs[i][tid];
    part[(size_t)tid * 512 + blk] = s;
  }
}

__global__ void __launch_bounds__(128) fc_stage2(const float* __restrict__ part,
                                                 const float* __restrict__ fb,
                                                 float* __restrict__ out) {
  int bc = threadIdx.x;
  float s = 0.f;
  for (int i = 0; i < 512; ++i) s += part[(size_t)bc * 512 + i];
  out[bc] = s + fb[bc & 15];
}

// ---------------- host launch ----------------
extern "C" void kernel_launch(void* const* d_in, const int* in_sizes, int n_in,
                              void* d_out, int out_size, void* d_ws, size_t ws_size,
                              hipStream_t stream) {
  (void)in_sizes; (void)n_in; (void)out_size; (void)ws_size;
  const float* x_enc  = (const float*)d_in[0];
  const float* x_mark = (const float*)d_in[1];
  const float* conv_w = (const float*)d_in[2];
  const float* Wq = (const float*)d_in[3];
  const float* bq = (const float*)d_in[4];
  const float* Wk = (const float*)d_in[5];
  const float* bk = (const float*)d_in[6];
  const float* Wv = (const float*)d_in[7];
  const float* bv = (const float*)d_in[8];
  const float* Wo = (const float*)d_in[9];
  const float* bo = (const float*)d_in[10];
  const float* W1 = (const float*)d_in[11];
  const float* b1 = (const float*)d_in[12];
  const float* W2 = (const float*)d_in[13];
  const float* b2 = (const float*)d_in[14];
  const float* g1 = (const float*)d_in[15];
  const float* be1= (const float*)d_in[16];
  const float* g2 = (const float*)d_in[17];
  const float* be2= (const float*)d_in[18];
  const float* gF = (const float*)d_in[19];
  const float* bF = (const float*)d_in[20];
  const float* fcw= (const float*)d_in[21];
  const float* fcb= (const float*)d_in[22];
  float* out = (float*)d_out;

  const size_t NBLD = (size_t)NB * LSEQ * DMODEL;       // 4,194,304
  float* ws  = (float*)d_ws;
  float* xb  = ws;
  float* tmp = xb  + NBLD;
  float* qb  = tmp + NBLD;       // qb,kb,vb contiguous (fused-QKV scatter)
  float* kb  = qb  + NBLD;
  float* vb  = kb  + NBLD;
  u16*  xh   = (u16*)(vb + NBLD);
  u16*  xl   = xh + NBLD;
  u16*  ch   = xl + NBLD;        // ctx hi
  u16*  cl   = ch + NBLD;        // ctx lo
  u16*  Whb  = cl + NBLD;        // per-layer weights hi
  u16*  Wlb  = Whb + 3145728;
  float* Mb  = (float*)(Wlb + 3145728);
  float* vm  = Mb + (size_t)NB * NH * LSEQ;
  float* part= vm + NB * NH * DH;
  int* idxb  = (int*)(part + 512 * 128);
  int* topb  = idxb + LSEQ * UTOP;
  u16* hidh  = (u16*)kb;
  u16* hidl  = (u16*)tmp;

  {
    dim3 gc(8, 32);
    conv_pe<<<gc, 256, 0, stream>>>(x_enc, conv_w, xb, xh, xl);
  }

  dim3 gqkv(12, 64);
  dim3 g512(4, 64);
  dim3 gff (16, 64);

  for (int l = 0; l < NLAYER; ++l) {
    cvt_split<<<262144/1024 + 1, 256, 0, stream>>>(Wq + (size_t)l*262144, Whb + 0,       Wlb + 0,       262144/4);
    cvt_split<<<262144/1024 + 1, 256, 0, stream>>>(Wk + (size_t)l*262144, Whb + 262144,  Wlb + 262144,  262144/4);
    cvt_split<<<262144/1024 + 1, 256, 0, stream>>>(Wv + (size_t)l*262144, Whb + 524288,  Wlb + 524288,  262144/4);
    cvt_split<<<262144/1024 + 1, 256, 0, stream>>>(Wo + (size_t)l*262144, Whb + 786432,  Wlb + 786432,  262144/4);
    cvt_split<<<1048576/1024 + 1, 256, 0, stream>>>(W1 + (size_t)l*1048576, Whb + 1048576, Wlb + 1048576, 1048576/4);
    cvt_split<<<1048576/1024 + 1, 256, 0, stream>>>(W2 + (size_t)l*1048576, Whb + 2097152, Wlb + 2097152, 1048576/4);

    gemm_bf16<<<gqkv, 256, 0, stream>>>(xh, xl, Whb, Wlb,
                                        bq + l*DMODEL, bk + l*DMODEL, bv + l*DMODEL,
                                        nullptr, qb, nullptr, nullptr,
                                        NB*LSEQ, 1536, DMODEL, 3);

    uint32_t lk0, lk1, k2_0, k2_1;
    tf2x32(0u, 42u, 0u, (uint32_t)l, lk0, lk1);
    tf2x32(lk0, lk1, 0u, 1u, k2_0, k2_1);
    gen_idx_kernel<<<140, 256, 0, stream>>>(k2_0, k2_1, idxb);
    sampled_m<<<NB * NH * LSEQ / 4, 256, 0, stream>>>(qb, kb, idxb, Mb);
    topk35<<<NB * NH, 256, 0, stream>>>(Mb, topb);
    vmean_k<<<NB * NH, 256, 0, stream>>>(vb, vm);
    ctx_fillb<<<(NB * NH * LSEQ * DH) / 1024, 256, 0, stream>>>(vm, ch, cl);
    attn_rows<<<448, 256, 0, stream>>>(qb, kb, vb, topb, ch, cl);

    gemm_bf16<<<g512, 256, 0, stream>>>(ch, cl, Whb + 786432, Wlb + 786432,
                                        bo + l*DMODEL, nullptr, nullptr,
                                        xb, qb, nullptr, nullptr,
                                        NB*LSEQ, DMODEL, DMODEL, 2);
    ln_k<<<NB * LSEQ, 256, 0, stream>>>(qb, g1 + l*DMODEL, be1 + l*DMODEL, xb, xh, xl, nullptr);

    gemm_bf16<<<gff, 256, 0, stream>>>(xh, xl, Whb + 1048576, Wlb + 1048576,
                                       b1 + l*DFF, nullptr, nullptr,
                                       nullptr, nullptr, hidh, hidl,
                                       NB*LSEQ, DFF, DMODEL, 1);
    gemm_bf16<<<g512, 256, 0, stream>>>(hidh, hidl, Whb + 2097152, Wlb + 2097152,
                                        b2 + l*DMODEL, nullptr, nullptr,
                                        xb, xb, nullptr, nullptr,
                                        NB*LSEQ, DMODEL, DFF, 2);
    ln_k<<<NB * LSEQ, 256, 0, stream>>>(xb, g2 + l*DMODEL, be2 + l*DMODEL, xb, xh, xl, nullptr);
  }

  ln_k<<<NB * LSEQ, 256, 0, stream>>>(xb, gF, bF, tmp, nullptr, nullptr, x_mark);
  fc_stage1<<<512, 256, 0, stream>>>(tmp, fcw, part);
  fc_stage2<<<1, 128, 0, stream>>>(part, fcb, out);
}